// Round 4
// baseline (370.079 us; speedup 1.0000x reference)
//
#include <hip/hip_runtime.h>
#include <math.h>

#define B_    8
#define NIN_  4096
#define P_    1024
#define K_    16
#define F_    64
#define CH_   67      // 3 + F
#define CPF_  64
#define CIN_  128
#define C_    128

// ---- ws float-offset layout ----
#define S_PF1  0
#define SH_PF1 64
#define S_PF2  128
#define SH_PF2 192
#define S_C1   256
#define SH_C1  512
#define S_C2   768
#define SH_C2  1024
#define S_C3   1280
#define SH_C3  1536
#define S_F    1792
#define SH_F   1920
#define M_OFF  2048     // fused pf matrix 3x64
#define C0_OFF 2240     // fused pf bias 64

// byte offsets in ws
#define WS_PTS_OFF  16384
#define WS_IDX_OFF  (WS_PTS_OFF + B_ * NIN_ * 16)          // 540672
#define WS_DWL_OFF  (WS_IDX_OFF + B_ * P_ * K_ * 4)        // 1064960

__device__ __forceinline__ float rlf(float x, int l) {
    return __int_as_float(__builtin_amdgcn_readlane(__float_as_int(x), l));
}
__device__ __forceinline__ float eluf(float z) {
    return z > 0.f ? z : expm1f(z);
}

// ---------------------------------------------------------------------------
// Kernel 0: fold BN params into scale/shift; collapse pf1+pf2 (no nonlinearity
// between them) into a single 3->64 affine (M, c0).
// ---------------------------------------------------------------------------
__global__ void bn_prep(const float* __restrict__ bn_pf1, const float* __restrict__ bn_pf2,
                        const float* __restrict__ bn_c1,  const float* __restrict__ bn_c2,
                        const float* __restrict__ bn_c3,  const float* __restrict__ bn_f,
                        const float* __restrict__ Wpf1,   const float* __restrict__ bpf1,
                        const float* __restrict__ Wpf2,   const float* __restrict__ bpf2,
                        float* __restrict__ wsf) {
    int t = threadIdx.x;
    {
        const float* src; int nch, c, so, sho;
        if (t < 64)       { src = bn_pf1; nch = 64;  c = t;        so = S_PF1; sho = SH_PF1; }
        else if (t < 128) { src = bn_pf2; nch = 64;  c = t - 64;   so = S_PF2; sho = SH_PF2; }
        else if (t < 384) { src = bn_c1;  nch = 256; c = t - 128;  so = S_C1;  sho = SH_C1; }
        else if (t < 640) { src = bn_c2;  nch = 256; c = t - 384;  so = S_C2;  sho = SH_C2; }
        else if (t < 896) { src = bn_c3;  nch = 256; c = t - 640;  so = S_C3;  sho = SH_C3; }
        else              { src = bn_f;   nch = 128; c = t - 896;  so = S_F;   sho = SH_F;  }
        float g = src[c], b = src[nch + c], m = src[2 * nch + c], v = src[3 * nch + c];
        float s = g * rsqrtf(v + 1e-3f);
        wsf[so + c]  = s;
        wsf[sho + c] = b - m * s;
    }
    __syncthreads();
    if (t < 64) {
        int o = t;
        float s2 = wsf[S_PF2 + o], t2 = wsf[SH_PF2 + o];
        float m0 = 0.f, m1 = 0.f, m2 = 0.f, cc = 0.f;
        for (int c = 0; c < 64; ++c) {
            float s1 = wsf[S_PF1 + c], t1 = wsf[SH_PF1 + c];
            float d1 = s1 * bpf1[c] + t1;
            float w2 = Wpf2[c * 64 + o];
            m0 += Wpf1[0 * 64 + c] * s1 * w2;
            m1 += Wpf1[1 * 64 + c] * s1 * w2;
            m2 += Wpf1[2 * 64 + c] * s1 * w2;
            cc += d1 * w2;
        }
        wsf[M_OFF + 0 * 64 + o] = m0 * s2;
        wsf[M_OFF + 1 * 64 + o] = m1 * s2;
        wsf[M_OFF + 2 * 64 + o] = m2 * s2;
        wsf[C0_OFF + o]         = cc * s2 + bpf2[o] * s2 + t2;
    }
}

// ---------------------------------------------------------------------------
// Kernel 0b: pack xyz + |p|^2 into float4 (pp bitwise-identical to reference)
// ---------------------------------------------------------------------------
__global__ __launch_bounds__(256) void pack_pts(const float* __restrict__ inp,
                                                float4* __restrict__ pts) {
    int i = blockIdx.x * 256 + threadIdx.x;
    if (i < B_ * NIN_) {
        const float* r = inp + (size_t)i * CH_;
        float x = r[0], y = r[1], z = r[2];
        float pp = __fadd_rn(__fadd_rn(__fmul_rn(x, x), __fmul_rn(y, y)),
                             __fmul_rn(z, z));
        pts[i] = make_float4(x, y, z, pp);
    }
}

// ---------------------------------------------------------------------------
// Kernel 1: exact KNN, TWO queries per wave. Lanes 0..31 hold query A's
// sorted top-32, lanes 32..63 query B's. One shfl_up pair advances both
// lists. Candidates scanned 32 at a time (shared by both halves).
// d2 bitwise-identical: d2 = (qq + pp) - (2*e), no FMA.
// ---------------------------------------------------------------------------
__global__ __launch_bounds__(256) void knn_kernel(const float4* __restrict__ pts,
                                                  int* __restrict__ idxo) {
    const int wv   = (blockIdx.x << 2) | (threadIdx.x >> 6);  // wave id 0..4095
    const int lane = threadIdx.x & 63;
    const int half = lane >> 5;          // 0 = query A, 1 = query B
    const int sl   = lane & 31;
    const int qid  = (wv << 1) | half;   // query id 0..8191 (same batch per wave)
    const float4* bp = pts + ((size_t)(qid >> 10) << 12);
    const int qi = qid & 1023;

    const float4 q = bp[qi];
    const float qq = q.w;

    // ---- group 0: candidates 0..31, bitonic sort by (d2, idx) within halves
    float4 p = bp[sl];
    float d; int ii = sl;
    {
        float e = __fadd_rn(__fadd_rn(__fmul_rn(q.x, p.x), __fmul_rn(q.y, p.y)),
                            __fmul_rn(q.z, p.z));
        d = __fsub_rn(__fadd_rn(qq, p.w), __fmul_rn(2.0f, e));
    }
#pragma unroll
    for (int k = 2; k <= 32; k <<= 1) {
#pragma unroll
        for (int j = k >> 1; j > 0; j >>= 1) {
            float od = __shfl_xor(d, j);          // j < 32: stays within half
            int   oi = __shfl_xor(ii, j);
            bool keepmin = (((sl & k) == 0) == ((sl & j) == 0));
            bool ol = (od < d) || (od == d && oi < ii);
            bool take = keepmin ? ol : !ol;
            if (take) { d = od; ii = oi; }
        }
    }
    float bd = d;      // sorted ascending within each half
    int   bi = ii;
    float kA = rlf(bd, 31), kB = rlf(bd, 63);
    float kth = half ? kB : kA;

    float4 pn = bp[32 + sl];
    for (int j0 = 32; j0 < NIN_; j0 += 32) {
        p = pn;
        if (j0 + 32 < NIN_) pn = bp[j0 + 32 + sl];
        float e  = __fadd_rn(__fadd_rn(__fmul_rn(q.x, p.x), __fmul_rn(q.y, p.y)),
                             __fmul_rn(q.z, p.z));
        float d2 = __fsub_rn(__fadd_rn(qq, p.w), __fmul_rn(2.0f, e));

        unsigned long long m = __ballot(d2 < kth);
        unsigned int mA = (unsigned int)m;
        unsigned int mB = (unsigned int)(m >> 32);
        while (mA | mB) {
            int cA = mA ? __builtin_ctz(mA) : 0;
            int cB = mB ? __builtin_ctz(mB) : 0;
            float dcA = rlf(d2, cA);
            float dcB = rlf(d2, 32 + cB);
            bool vA = (mA != 0) && (dcA < kA);    // re-check vs tightened kth
            bool vB = (mB != 0) && (dcB < kB);
            if (mA) mA &= mA - 1;
            if (mB) mB &= mB - 1;
            if (!(vA || vB)) continue;
            float dc = half ? (vB ? dcB : 1e38f) : (vA ? dcA : 1e38f);
            int   ic = j0 + (half ? cB : cA);
            float prev  = __shfl_up(bd, 1);
            int   previ = __shfl_up(bi, 1);
            bool shift = (bd > dc);               // strict: ties keep lower idx
            bool ins   = shift && ((sl == 0) || (prev <= dc));
            if (shift) { bd = prev; bi = previ; }
            if (ins)   { bd = dc;   bi = ic;    }
            kA = rlf(bd, 31); kB = rlf(bd, 63);
            kth = half ? kB : kA;
        }
    }

    // dilated take: ranks 0,2,...,30 per half
    if (!(sl & 1)) {
        idxo[((size_t)qid << 4) | (sl >> 1)] = bi;
    }
}

// ---------------------------------------------------------------------------
// Kernel 2: stages A..H. One wave per point, 4 waves/block, no barriers.
// fnb gather issued FIRST (consumed only in stage G -> latency hidden under
// D/E/F). xyz gather is a single load instr (lanes 0..47, k=l/3, d=l%3).
// h2 (fused pf) computed late in stage G from LDS pnb broadcasts.
// ---------------------------------------------------------------------------
__global__ __launch_bounds__(256, 4) void p1_kernel(
    const float* __restrict__ inp, const int* __restrict__ idx,
    const float* __restrict__ Wc1,  const float* __restrict__ bc1,
    const float* __restrict__ Wc2,  const float* __restrict__ bc2,
    const float* __restrict__ Wc3,  const float* __restrict__ bc3,
    const float* __restrict__ Wdf,  const float* __restrict__ wsf,
    float* __restrict__ dwl, float* __restrict__ out) {

    __shared__ float pnb[4][64];     // p_nb flat (48 used)
    __shared__ float xA[4][256];
    __shared__ float xB[4][256];

    const int w  = threadIdx.x >> 6;
    const int l  = threadIdx.x & 63;
    const int ng = blockIdx.x * 4 + w;       // global point id
    const int b  = ng >> 10;
    const int n  = ng & 1023;
    const float* brow = inp + (size_t)b * NIN_ * CH_;
    const int* ip = idx + (size_t)ng * K_;

    // neighbor indices (wave-uniform values), then issue fnb gathers EARLY
    int nb[16];
#pragma unroll
    for (int k = 0; k < 16; ++k) nb[k] = ip[k];
    float fnb[16];
#pragma unroll
    for (int k = 0; k < 16; ++k) fnb[k] = brow[(size_t)nb[k] * CH_ + 3 + l];

    const float q0 = brow[(size_t)n * CH_ + 0];
    const float q1 = brow[(size_t)n * CH_ + 1];
    const float q2 = brow[(size_t)n * CH_ + 2];

    // xyz gather: one load instr, lanes 0..47: k = l/3, d = l%3
    {
        int k3 = (l * 21846) >> 16;          // l/3 for l < 48
        k3 = (k3 > 15) ? 15 : k3;
        int d3 = l - ((k3 << 1) + k3);
        d3 = (d3 > 2) ? 2 : d3;
        int nbl = ip[k3];                    // per-lane load within one 64B row
        float v = 0.f;
        if (l < 48) v = brow[(size_t)nbl * CH_ + d3];
        float qv = (d3 == 0) ? q0 : ((d3 == 1) ? q1 : q2);
        if (l < 48) pnb[w][l] = v - qv;
    }

    // ---- Stage D: x1[o] = BN(elu(pnb48 . Wc1 + bc1)),  o = 4l+r
    {
        float4 acc = *reinterpret_cast<const float4*>(bc1 + 4 * l);
#pragma unroll
        for (int t12 = 0; t12 < 12; ++t12) {
            float4 pv = *reinterpret_cast<const float4*>(&pnb[w][t12 * 4]);
            const float* wb = Wc1 + (size_t)(t12 * 4) * 256 + 4 * l;
            float4 w0 = *reinterpret_cast<const float4*>(wb);
            float4 w1 = *reinterpret_cast<const float4*>(wb + 256);
            float4 w2 = *reinterpret_cast<const float4*>(wb + 512);
            float4 w3 = *reinterpret_cast<const float4*>(wb + 768);
            acc.x += pv.x * w0.x + pv.y * w1.x + pv.z * w2.x + pv.w * w3.x;
            acc.y += pv.x * w0.y + pv.y * w1.y + pv.z * w2.y + pv.w * w3.y;
            acc.z += pv.x * w0.z + pv.y * w1.z + pv.z * w2.z + pv.w * w3.z;
            acc.w += pv.x * w0.w + pv.y * w1.w + pv.z * w2.w + pv.w * w3.w;
        }
        float4 sc = *reinterpret_cast<const float4*>(wsf + S_C1 + 4 * l);
        float4 sh = *reinterpret_cast<const float4*>(wsf + SH_C1 + 4 * l);
        float4 r;
        r.x = sc.x * eluf(acc.x) + sh.x;
        r.y = sc.y * eluf(acc.y) + sh.y;
        r.z = sc.z * eluf(acc.z) + sh.z;
        r.w = sc.w * eluf(acc.w) + sh.w;
        *reinterpret_cast<float4*>(&xA[w][4 * l]) = r;
    }

    // ---- Stage E: x2[o] = BN(elu(sum_w x1[w][c]*Wc2[w][o])),  c = l>>2
    {
        float4 acc = *reinterpret_cast<const float4*>(bc2 + 4 * l);
        const int csel = l >> 2;
#pragma unroll
        for (int w16 = 0; w16 < 16; ++w16) {
            float xs = xA[w][w16 * 16 + csel];
            float4 w4 = *reinterpret_cast<const float4*>(Wc2 + (size_t)w16 * 256 + 4 * l);
            acc.x += xs * w4.x; acc.y += xs * w4.y;
            acc.z += xs * w4.z; acc.w += xs * w4.w;
        }
        float4 sc = *reinterpret_cast<const float4*>(wsf + S_C2 + 4 * l);
        float4 sh = *reinterpret_cast<const float4*>(wsf + SH_C2 + 4 * l);
        float4 r;
        r.x = sc.x * eluf(acc.x) + sh.x;
        r.y = sc.y * eluf(acc.y) + sh.y;
        r.z = sc.z * eluf(acc.z) + sh.z;
        r.w = sc.w * eluf(acc.w) + sh.w;
        *reinterpret_cast<float4*>(&xB[w][4 * l]) = r;
    }

    // ---- Stage F: x3 (kept in registers, o = 4l..4l+3)
    float x3r[4];
    {
        float4 acc = *reinterpret_cast<const float4*>(bc3 + 4 * l);
        const int csel = l >> 2;
#pragma unroll
        for (int w16 = 0; w16 < 16; ++w16) {
            float xs = xB[w][w16 * 16 + csel];
            float4 w4 = *reinterpret_cast<const float4*>(Wc3 + (size_t)w16 * 256 + 4 * l);
            acc.x += xs * w4.x; acc.y += xs * w4.y;
            acc.z += xs * w4.z; acc.w += xs * w4.w;
        }
        float4 sc = *reinterpret_cast<const float4*>(wsf + S_C3 + 4 * l);
        float4 sh = *reinterpret_cast<const float4*>(wsf + SH_C3 + 4 * l);
        x3r[0] = sc.x * eluf(acc.x) + sh.x;
        x3r[1] = sc.y * eluf(acc.y) + sh.y;
        x3r[2] = sc.z * eluf(acc.z) + sh.z;
        x3r[3] = sc.w * eluf(acc.w) + sh.w;
    }

    // ---- h2 (fused pf) computed late: LDS broadcasts of pnb + M regs
    const float Mw0 = wsf[M_OFF + l];
    const float Mw1 = wsf[M_OFF + 64 + l];
    const float Mw2 = wsf[M_OFF + 128 + l];
    const float cc0 = wsf[C0_OFF + l];
    float h2[16];
#pragma unroll
    for (int k = 0; k < 16; ++k) {
        float s0 = pnb[w][3 * k], s1 = pnb[w][3 * k + 1], s2 = pnb[w][3 * k + 2];
        h2[k] = fmaf(s0, Mw0, fmaf(s1, Mw1, fmaf(s2, Mw2, cc0)));
    }

    // ---- Stage G+H fused: feat2 row i folded straight into dw
    float d00 = 0.f, d01 = 0.f, d10 = 0.f, d11 = 0.f;
#pragma unroll
    for (int i = 0; i < 16; ++i) {
        float fa = 0.f, fb = 0.f;
#pragma unroll
        for (int j = 0; j < 16; ++j) {
            const int o = i * 16 + j;
            float xv = rlf(x3r[o & 3], o >> 2);
            fa += xv * h2[j];
            fb += xv * fnb[j];
        }
        const float* wr = Wdf + (size_t)i * 256;
        float2 wlo = *reinterpret_cast<const float2*>(wr + 2 * l);
        float2 whi = *reinterpret_cast<const float2*>(wr + 128 + 2 * l);
        d00 += fa * wlo.x; d01 += fa * wlo.y;
        d10 += fb * whi.x; d11 += fb * whi.y;
    }
    float* drow = dwl + (size_t)ng * 256;
    *reinterpret_cast<float2*>(drow + 2 * l)       = make_float2(d00, d01);
    *reinterpret_cast<float2*>(drow + 128 + 2 * l) = make_float2(d10, d11);

    if (l < 3) out[(size_t)ng * 131 + l] = (l == 0) ? q0 : ((l == 1) ? q1 : q2);
}

// ---------------------------------------------------------------------------
// Kernel 3: final pointwise layer as tiled f32 GEMM: M=8192 K=256 N=128.
// ---------------------------------------------------------------------------
__global__ __launch_bounds__(256) void pw_kernel(const float* __restrict__ dwl,
                                                 const float* __restrict__ Wpw,
                                                 const float* __restrict__ bf,
                                                 const float* __restrict__ wsf,
                                                 float* __restrict__ out) {
    __shared__ float As[32][256];
    const int tid = threadIdx.x;
    const int m0  = blockIdx.x * 32;

#pragma unroll
    for (int i = 0; i < 8; ++i) {
        int fi  = i * 1024 + tid * 4;
        int row = fi >> 8, col = fi & 255;
        *reinterpret_cast<float4*>(&As[row][col]) =
            *reinterpret_cast<const float4*>(dwl + (size_t)(m0 + row) * 256 + col);
    }
    __syncthreads();

    const int mq = tid >> 5;          // 8 m-quads
    const int nq = tid & 31;          // 32 n-quads
    float acc[4][4];
#pragma unroll
    for (int mi = 0; mi < 4; ++mi)
#pragma unroll
        for (int ni = 0; ni < 4; ++ni) acc[mi][ni] = 0.f;

#pragma unroll 4
    for (int k4 = 0; k4 < 64; ++k4) {
        float4 a[4], bw[4];
#pragma unroll
        for (int mi = 0; mi < 4; ++mi)
            a[mi] = *reinterpret_cast<const float4*>(&As[mq * 4 + mi][k4 * 4]);
#pragma unroll
        for (int ki = 0; ki < 4; ++ki)
            bw[ki] = *reinterpret_cast<const float4*>(Wpw + (size_t)(k4 * 4 + ki) * 128 + nq * 4);
#pragma unroll
        for (int mi = 0; mi < 4; ++mi) {
            const float4 am = a[mi];
            acc[mi][0] += am.x * bw[0].x + am.y * bw[1].x + am.z * bw[2].x + am.w * bw[3].x;
            acc[mi][1] += am.x * bw[0].y + am.y * bw[1].y + am.z * bw[2].y + am.w * bw[3].y;
            acc[mi][2] += am.x * bw[0].z + am.y * bw[1].z + am.z * bw[2].z + am.w * bw[3].z;
            acc[mi][3] += am.x * bw[0].w + am.y * bw[1].w + am.z * bw[2].w + am.w * bw[3].w;
        }
    }

    float4 b4  = *reinterpret_cast<const float4*>(bf + nq * 4);
    float4 sc4 = *reinterpret_cast<const float4*>(wsf + S_F + nq * 4);
    float4 sh4 = *reinterpret_cast<const float4*>(wsf + SH_F + nq * 4);
#pragma unroll
    for (int mi = 0; mi < 4; ++mi) {
        const int m = m0 + mq * 4 + mi;
        float* orow = out + (size_t)m * 131 + 3 + nq * 4;
        orow[0] = sc4.x * eluf(acc[mi][0] + b4.x) + sh4.x;
        orow[1] = sc4.y * eluf(acc[mi][1] + b4.y) + sh4.y;
        orow[2] = sc4.z * eluf(acc[mi][2] + b4.z) + sh4.z;
        orow[3] = sc4.w * eluf(acc[mi][3] + b4.w) + sh4.w;
    }
}

// ---------------------------------------------------------------------------
extern "C" void kernel_launch(void* const* d_in, const int* in_sizes, int n_in,
                              void* d_out, int out_size, void* d_ws, size_t ws_size,
                              hipStream_t stream) {
    const float* inp   = (const float*)d_in[0];
    const float* Wpf1  = (const float*)d_in[1];
    const float* bpf1  = (const float*)d_in[2];
    const float* bnpf1 = (const float*)d_in[3];
    const float* Wpf2  = (const float*)d_in[4];
    const float* bpf2  = (const float*)d_in[5];
    const float* bnpf2 = (const float*)d_in[6];
    const float* Wc1   = (const float*)d_in[7];
    const float* bc1   = (const float*)d_in[8];
    const float* bnc1  = (const float*)d_in[9];
    const float* Wc2   = (const float*)d_in[10];
    const float* bc2   = (const float*)d_in[11];
    const float* bnc2  = (const float*)d_in[12];
    const float* Wc3   = (const float*)d_in[13];
    const float* bc3   = (const float*)d_in[14];
    const float* bnc3  = (const float*)d_in[15];
    const float* Wdf   = (const float*)d_in[16];
    const float* Wpw   = (const float*)d_in[17];
    const float* bf    = (const float*)d_in[18];
    const float* bnf   = (const float*)d_in[19];

    float*  wsf  = (float*)d_ws;
    float4* pts  = (float4*)((char*)d_ws + WS_PTS_OFF);
    int*    idxw = (int*)((char*)d_ws + WS_IDX_OFF);
    float*  dwl  = (float*)((char*)d_ws + WS_DWL_OFF);
    float*  outp = (float*)d_out;

    hipLaunchKernelGGL(bn_prep, dim3(1), dim3(1024), 0, stream,
                       bnpf1, bnpf2, bnc1, bnc2, bnc3, bnf,
                       Wpf1, bpf1, Wpf2, bpf2, wsf);
    hipLaunchKernelGGL(pack_pts, dim3((B_ * NIN_ + 255) / 256), dim3(256), 0, stream,
                       inp, pts);
    hipLaunchKernelGGL(knn_kernel, dim3((B_ * P_) / 8), dim3(256), 0, stream,
                       pts, idxw);
    hipLaunchKernelGGL(p1_kernel, dim3((B_ * P_) / 4), dim3(256), 0, stream,
                       inp, idxw, Wc1, bc1, Wc2, bc2, Wc3, bc3, Wdf, wsf,
                       dwl, outp);
    hipLaunchKernelGGL(pw_kernel, dim3((B_ * P_) / 32), dim3(256), 0, stream,
                       dwl, Wpw, bf, wsf, outp);
}

// Round 5
// 129.077 us; speedup vs baseline: 2.8671x; 2.8671x over previous
//
#include <hip/hip_runtime.h>
#include <math.h>

#define B_    8
#define NIN_  4096
#define P_    1024
#define K_    16
#define F_    64
#define CH_   67      // 3 + F
#define CPF_  64
#define CIN_  128
#define C_    128

// ---- ws float-offset layout ----
#define S_PF1  0
#define SH_PF1 64
#define S_PF2  128
#define SH_PF2 192
#define S_C1   256
#define SH_C1  512
#define S_C2   768
#define SH_C2  1024
#define S_C3   1280
#define SH_C3  1536
#define S_F    1792
#define SH_F   1920
#define M_OFF  2048     // fused pf matrix 3x64
#define C0_OFF 2240     // fused pf bias 64

// byte offsets in ws
#define WS_PTS_OFF  16384
#define WS_IDX_OFF  (WS_PTS_OFF + B_ * NIN_ * 16)          // 540672
#define WS_DWL_OFF  (WS_IDX_OFF + B_ * P_ * K_ * 4)        // 1064960

__device__ __forceinline__ float rlf(float x, int l) {
    return __int_as_float(__builtin_amdgcn_readlane(__float_as_int(x), l));
}
__device__ __forceinline__ float eluf(float z) {
    return z > 0.f ? z : expm1f(z);
}

// ---------------------------------------------------------------------------
// Kernel 0: fold BN params into scale/shift; collapse pf1+pf2 (no nonlinearity
// between them) into a single 3->64 affine (M, c0).
// ---------------------------------------------------------------------------
__global__ void bn_prep(const float* __restrict__ bn_pf1, const float* __restrict__ bn_pf2,
                        const float* __restrict__ bn_c1,  const float* __restrict__ bn_c2,
                        const float* __restrict__ bn_c3,  const float* __restrict__ bn_f,
                        const float* __restrict__ Wpf1,   const float* __restrict__ bpf1,
                        const float* __restrict__ Wpf2,   const float* __restrict__ bpf2,
                        float* __restrict__ wsf) {
    int t = threadIdx.x;
    {
        const float* src; int nch, c, so, sho;
        if (t < 64)       { src = bn_pf1; nch = 64;  c = t;        so = S_PF1; sho = SH_PF1; }
        else if (t < 128) { src = bn_pf2; nch = 64;  c = t - 64;   so = S_PF2; sho = SH_PF2; }
        else if (t < 384) { src = bn_c1;  nch = 256; c = t - 128;  so = S_C1;  sho = SH_C1; }
        else if (t < 640) { src = bn_c2;  nch = 256; c = t - 384;  so = S_C2;  sho = SH_C2; }
        else if (t < 896) { src = bn_c3;  nch = 256; c = t - 640;  so = S_C3;  sho = SH_C3; }
        else              { src = bn_f;   nch = 128; c = t - 896;  so = S_F;   sho = SH_F;  }
        float g = src[c], b = src[nch + c], m = src[2 * nch + c], v = src[3 * nch + c];
        float s = g * rsqrtf(v + 1e-3f);
        wsf[so + c]  = s;
        wsf[sho + c] = b - m * s;
    }
    __syncthreads();
    if (t < 64) {
        int o = t;
        float s2 = wsf[S_PF2 + o], t2 = wsf[SH_PF2 + o];
        float m0 = 0.f, m1 = 0.f, m2 = 0.f, cc = 0.f;
        for (int c = 0; c < 64; ++c) {
            float s1 = wsf[S_PF1 + c], t1 = wsf[SH_PF1 + c];
            float d1 = s1 * bpf1[c] + t1;
            float w2 = Wpf2[c * 64 + o];
            m0 += Wpf1[0 * 64 + c] * s1 * w2;
            m1 += Wpf1[1 * 64 + c] * s1 * w2;
            m2 += Wpf1[2 * 64 + c] * s1 * w2;
            cc += d1 * w2;
        }
        wsf[M_OFF + 0 * 64 + o] = m0 * s2;
        wsf[M_OFF + 1 * 64 + o] = m1 * s2;
        wsf[M_OFF + 2 * 64 + o] = m2 * s2;
        wsf[C0_OFF + o]         = cc * s2 + bpf2[o] * s2 + t2;
    }
}

// ---------------------------------------------------------------------------
// Kernel 0b: pack xyz + |p|^2 into float4 (pp bitwise-identical to reference)
// ---------------------------------------------------------------------------
__global__ __launch_bounds__(256) void pack_pts(const float* __restrict__ inp,
                                                float4* __restrict__ pts) {
    int i = blockIdx.x * 256 + threadIdx.x;
    if (i < B_ * NIN_) {
        const float* r = inp + (size_t)i * CH_;
        float x = r[0], y = r[1], z = r[2];
        float pp = __fadd_rn(__fadd_rn(__fmul_rn(x, x), __fmul_rn(y, y)),
                             __fmul_rn(z, z));
        pts[i] = make_float4(x, y, z, pp);
    }
}

// ---------------------------------------------------------------------------
// Kernel 1: exact KNN (REVERTED to the round-3-verified version).
// One wave per query; sorted top-32 across lanes 0..31. First 64 candidates
// via cross-lane bitonic sort keyed (d2, idx); remaining via wave-parallel
// shfl insertion with readlane broadcasts.
// d2 bitwise-identical: d2 = (qq + pp) - (2*e), no FMA.
// ---------------------------------------------------------------------------
__global__ __launch_bounds__(256) void knn_kernel(const float4* __restrict__ pts,
                                                  int* __restrict__ idxo) {
    const int wid  = (blockIdx.x << 2) | (threadIdx.x >> 6);  // query id 0..8191
    const int lane = threadIdx.x & 63;
    const float4* bp = pts + ((size_t)(wid >> 10) << 12);
    const int qi = wid & 1023;

    const float4 q = bp[qi];
    const float qq = q.w;

    // ---- group 0: bitonic sort 64 candidates by (d2, idx) ascending
    float4 p = bp[lane];
    float d;
    {
        float e = __fadd_rn(__fadd_rn(__fmul_rn(q.x, p.x), __fmul_rn(q.y, p.y)),
                            __fmul_rn(q.z, p.z));
        d = __fsub_rn(__fadd_rn(qq, p.w), __fmul_rn(2.0f, e));
    }
    int ii = lane;
#pragma unroll
    for (int k = 2; k <= 64; k <<= 1) {
#pragma unroll
        for (int j = k >> 1; j > 0; j >>= 1) {
            float od = __shfl_xor(d, j);
            int   oi = __shfl_xor(ii, j);
            bool keepmin = (((lane & k) == 0) == ((lane & j) == 0));
            bool ol = (od < d) || (od == d && oi < ii);
            bool take = keepmin ? ol : !ol;
            if (take) { d = od; ii = oi; }
        }
    }
    float bd = d;      // lane s (<32): s-th smallest
    int   bi = ii;
    float kth = rlf(bd, 31);

    float4 pn = bp[64 + lane];
    for (int j0 = 64; j0 < NIN_; j0 += 64) {
        p = pn;
        if (j0 + 64 < NIN_) pn = bp[j0 + 64 + lane];
        float e  = __fadd_rn(__fadd_rn(__fmul_rn(q.x, p.x), __fmul_rn(q.y, p.y)),
                             __fmul_rn(q.z, p.z));
        float d2 = __fsub_rn(__fadd_rn(qq, p.w), __fmul_rn(2.0f, e));

        unsigned long long m = __ballot(d2 < kth);
        while (m) {
            int c = __builtin_ctzll(m);
            m &= m - 1;
            float dc = rlf(d2, c);          // uniform (SGPR) broadcast
            if (dc < kth) {                 // uniform branch
                int   ic    = j0 + c;
                float prev  = __shfl_up(bd, 1);
                int   previ = __shfl_up(bi, 1);
                bool  shift = (bd > dc);    // strict: ties keep lower index first
                bool  ins   = shift && ((lane == 0) || (prev <= dc));
                if (shift) { bd = prev; bi = previ; }
                if (ins)   { bd = dc;   bi = ic;    }
                kth = rlf(bd, 31);
            }
        }
    }

    if (lane < 32 && !(lane & 1)) {
        idxo[((size_t)wid << 4) | (lane >> 1)] = bi;
    }
}

// ---------------------------------------------------------------------------
// Kernel 2: stages A..H. One wave per point, 4 waves/block, no barriers.
// Register-liveness-driven design:
//  - pnb lives as ONE reg/lane (pd), consumed via v_readlane in D and G.
//  - fnb loaded from global LATE (just before G) -> short liveness.
//  - neighbor bases in SGPRs via readfirstlane.
//  - partial unrolls cap in-flight weight loads.
// ---------------------------------------------------------------------------
__global__ __launch_bounds__(256) void p1_kernel(
    const float* __restrict__ inp, const int* __restrict__ idx,
    const float* __restrict__ Wc1,  const float* __restrict__ bc1,
    const float* __restrict__ Wc2,  const float* __restrict__ bc2,
    const float* __restrict__ Wc3,  const float* __restrict__ bc3,
    const float* __restrict__ Wdf,  const float* __restrict__ wsf,
    float* __restrict__ dwl, float* __restrict__ out) {

    __shared__ float xA[4][256];
    __shared__ float xB[4][256];

    const int w  = threadIdx.x >> 6;
    const int l  = threadIdx.x & 63;
    const int ng = blockIdx.x * 4 + w;       // global point id
    const int b  = ng >> 10;
    const int n  = ng & 1023;
    const float* brow = inp + (size_t)b * NIN_ * CH_;
    const int* ip = idx + (size_t)ng * K_;

    const float q0 = brow[(size_t)n * CH_ + 0];
    const float q1 = brow[(size_t)n * CH_ + 1];
    const float q2 = brow[(size_t)n * CH_ + 2];

    // ---- xyz gather: ONE load instr. lanes 0..47: k = l/3, d = l%3.
    // pd (lane tt) = p_nb flat element tt; lanes 48..63 unused.
    float pd;
    {
        int k3 = (l * 21846) >> 16;          // l/3 for l < 48
        k3 = (k3 > 15) ? 15 : k3;
        int d3 = l - ((k3 << 1) + k3);
        d3 = (d3 > 2) ? 2 : d3;
        int nbl = ip[k3];                    // per-lane load (64B of idx row)
        float v = 0.f;
        if (l < 48) v = brow[(size_t)nbl * CH_ + d3];
        float qv = (d3 == 0) ? q0 : ((d3 == 1) ? q1 : q2);
        pd = v - qv;
    }

    // ---- Stage D: x1[o] = BN(elu(pnb48 . Wc1 + bc1)),  o = 4l+r
    {
        float4 acc = *reinterpret_cast<const float4*>(bc1 + 4 * l);
#pragma unroll 4
        for (int t4 = 0; t4 < 12; ++t4) {
            const float* wb = Wc1 + (size_t)(t4 * 4) * 256 + 4 * l;
            float4 w0 = *reinterpret_cast<const float4*>(wb);
            float4 w1 = *reinterpret_cast<const float4*>(wb + 256);
            float4 w2 = *reinterpret_cast<const float4*>(wb + 512);
            float4 w3 = *reinterpret_cast<const float4*>(wb + 768);
            float p0 = rlf(pd, 4 * t4 + 0);
            float p1 = rlf(pd, 4 * t4 + 1);
            float p2 = rlf(pd, 4 * t4 + 2);
            float p3 = rlf(pd, 4 * t4 + 3);
            acc.x += p0 * w0.x + p1 * w1.x + p2 * w2.x + p3 * w3.x;
            acc.y += p0 * w0.y + p1 * w1.y + p2 * w2.y + p3 * w3.y;
            acc.z += p0 * w0.z + p1 * w1.z + p2 * w2.z + p3 * w3.z;
            acc.w += p0 * w0.w + p1 * w1.w + p2 * w2.w + p3 * w3.w;
        }
        float4 sc = *reinterpret_cast<const float4*>(wsf + S_C1 + 4 * l);
        float4 sh = *reinterpret_cast<const float4*>(wsf + SH_C1 + 4 * l);
        float4 r;
        r.x = sc.x * eluf(acc.x) + sh.x;
        r.y = sc.y * eluf(acc.y) + sh.y;
        r.z = sc.z * eluf(acc.z) + sh.z;
        r.w = sc.w * eluf(acc.w) + sh.w;
        *reinterpret_cast<float4*>(&xA[w][4 * l]) = r;
    }

    // ---- Stage E: x2[o] = BN(elu(sum_w x1[w][c]*Wc2[w][o])),  c = l>>2
    {
        float4 acc = *reinterpret_cast<const float4*>(bc2 + 4 * l);
        const int csel = l >> 2;
#pragma unroll 8
        for (int w16 = 0; w16 < 16; ++w16) {
            float xs = xA[w][w16 * 16 + csel];
            float4 w4 = *reinterpret_cast<const float4*>(Wc2 + (size_t)w16 * 256 + 4 * l);
            acc.x += xs * w4.x; acc.y += xs * w4.y;
            acc.z += xs * w4.z; acc.w += xs * w4.w;
        }
        float4 sc = *reinterpret_cast<const float4*>(wsf + S_C2 + 4 * l);
        float4 sh = *reinterpret_cast<const float4*>(wsf + SH_C2 + 4 * l);
        float4 r;
        r.x = sc.x * eluf(acc.x) + sh.x;
        r.y = sc.y * eluf(acc.y) + sh.y;
        r.z = sc.z * eluf(acc.z) + sh.z;
        r.w = sc.w * eluf(acc.w) + sh.w;
        *reinterpret_cast<float4*>(&xB[w][4 * l]) = r;
    }

    // ---- Stage F: x3 (kept in registers, o = 4l..4l+3)
    float x3r[4];
    {
        float4 acc = *reinterpret_cast<const float4*>(bc3 + 4 * l);
        const int csel = l >> 2;
#pragma unroll 8
        for (int w16 = 0; w16 < 16; ++w16) {
            float xs = xB[w][w16 * 16 + csel];
            float4 w4 = *reinterpret_cast<const float4*>(Wc3 + (size_t)w16 * 256 + 4 * l);
            acc.x += xs * w4.x; acc.y += xs * w4.y;
            acc.z += xs * w4.z; acc.w += xs * w4.w;
        }
        float4 sc = *reinterpret_cast<const float4*>(wsf + S_C3 + 4 * l);
        float4 sh = *reinterpret_cast<const float4*>(wsf + SH_C3 + 4 * l);
        x3r[0] = sc.x * eluf(acc.x) + sh.x;
        x3r[1] = sc.y * eluf(acc.y) + sh.y;
        x3r[2] = sc.z * eluf(acc.z) + sh.z;
        x3r[3] = sc.w * eluf(acc.w) + sh.w;
    }

    // ---- h2 (fused pf) from readlanes of pd (short liveness)
    float h2[16];
    {
        const float Mw0 = wsf[M_OFF + l];
        const float Mw1 = wsf[M_OFF + 64 + l];
        const float Mw2 = wsf[M_OFF + 128 + l];
        const float cc0 = wsf[C0_OFF + l];
#pragma unroll
        for (int k = 0; k < 16; ++k) {
            float s0 = rlf(pd, 3 * k), s1 = rlf(pd, 3 * k + 1), s2 = rlf(pd, 3 * k + 2);
            h2[k] = fmaf(s0, Mw0, fmaf(s1, Mw1, fmaf(s2, Mw2, cc0)));
        }
    }

    // ---- fnb loaded LATE from global (SGPR row bases via readfirstlane)
    float fnb[16];
#pragma unroll
    for (int k = 0; k < 16; ++k) {
        int nbs = __builtin_amdgcn_readfirstlane(ip[k]);
        fnb[k] = brow[(size_t)nbs * CH_ + 3 + l];
    }

    // ---- Stage G+H fused: feat2 row i folded straight into dw
    float d00 = 0.f, d01 = 0.f, d10 = 0.f, d11 = 0.f;
#pragma unroll 4
    for (int i = 0; i < 16; ++i) {
        float fa = 0.f, fb = 0.f;
#pragma unroll
        for (int j = 0; j < 16; ++j) {
            float xv = rlf(x3r[j & 3], i * 4 + (j >> 2));
            fa += xv * h2[j];
            fb += xv * fnb[j];
        }
        const float* wr = Wdf + (size_t)i * 256;
        float2 wlo = *reinterpret_cast<const float2*>(wr + 2 * l);
        float2 whi = *reinterpret_cast<const float2*>(wr + 128 + 2 * l);
        d00 += fa * wlo.x; d01 += fa * wlo.y;
        d10 += fb * whi.x; d11 += fb * whi.y;
    }
    float* drow = dwl + (size_t)ng * 256;
    *reinterpret_cast<float2*>(drow + 2 * l)       = make_float2(d00, d01);
    *reinterpret_cast<float2*>(drow + 128 + 2 * l) = make_float2(d10, d11);

    if (l < 3) out[(size_t)ng * 131 + l] = (l == 0) ? q0 : ((l == 1) ? q1 : q2);
}

// ---------------------------------------------------------------------------
// Kernel 3: final pointwise layer as tiled f32 GEMM: M=8192 K=256 N=128.
// ---------------------------------------------------------------------------
__global__ __launch_bounds__(256) void pw_kernel(const float* __restrict__ dwl,
                                                 const float* __restrict__ Wpw,
                                                 const float* __restrict__ bf,
                                                 const float* __restrict__ wsf,
                                                 float* __restrict__ out) {
    __shared__ float As[32][256];
    const int tid = threadIdx.x;
    const int m0  = blockIdx.x * 32;

#pragma unroll
    for (int i = 0; i < 8; ++i) {
        int fi  = i * 1024 + tid * 4;
        int row = fi >> 8, col = fi & 255;
        *reinterpret_cast<float4*>(&As[row][col]) =
            *reinterpret_cast<const float4*>(dwl + (size_t)(m0 + row) * 256 + col);
    }
    __syncthreads();

    const int mq = tid >> 5;          // 8 m-quads
    const int nq = tid & 31;          // 32 n-quads
    float acc[4][4];
#pragma unroll
    for (int mi = 0; mi < 4; ++mi)
#pragma unroll
        for (int ni = 0; ni < 4; ++ni) acc[mi][ni] = 0.f;

#pragma unroll 4
    for (int k4 = 0; k4 < 64; ++k4) {
        float4 a[4], bw[4];
#pragma unroll
        for (int mi = 0; mi < 4; ++mi)
            a[mi] = *reinterpret_cast<const float4*>(&As[mq * 4 + mi][k4 * 4]);
#pragma unroll
        for (int ki = 0; ki < 4; ++ki)
            bw[ki] = *reinterpret_cast<const float4*>(Wpw + (size_t)(k4 * 4 + ki) * 128 + nq * 4);
#pragma unroll
        for (int mi = 0; mi < 4; ++mi) {
            const float4 am = a[mi];
            acc[mi][0] += am.x * bw[0].x + am.y * bw[1].x + am.z * bw[2].x + am.w * bw[3].x;
            acc[mi][1] += am.x * bw[0].y + am.y * bw[1].y + am.z * bw[2].y + am.w * bw[3].y;
            acc[mi][2] += am.x * bw[0].z + am.y * bw[1].z + am.z * bw[2].z + am.w * bw[3].z;
            acc[mi][3] += am.x * bw[0].w + am.y * bw[1].w + am.z * bw[2].w + am.w * bw[3].w;
        }
    }

    float4 b4  = *reinterpret_cast<const float4*>(bf + nq * 4);
    float4 sc4 = *reinterpret_cast<const float4*>(wsf + S_F + nq * 4);
    float4 sh4 = *reinterpret_cast<const float4*>(wsf + SH_F + nq * 4);
#pragma unroll
    for (int mi = 0; mi < 4; ++mi) {
        const int m = m0 + mq * 4 + mi;
        float* orow = out + (size_t)m * 131 + 3 + nq * 4;
        orow[0] = sc4.x * eluf(acc[mi][0] + b4.x) + sh4.x;
        orow[1] = sc4.y * eluf(acc[mi][1] + b4.y) + sh4.y;
        orow[2] = sc4.z * eluf(acc[mi][2] + b4.z) + sh4.z;
        orow[3] = sc4.w * eluf(acc[mi][3] + b4.w) + sh4.w;
    }
}

// ---------------------------------------------------------------------------
extern "C" void kernel_launch(void* const* d_in, const int* in_sizes, int n_in,
                              void* d_out, int out_size, void* d_ws, size_t ws_size,
                              hipStream_t stream) {
    const float* inp   = (const float*)d_in[0];
    const float* Wpf1  = (const float*)d_in[1];
    const float* bpf1  = (const float*)d_in[2];
    const float* bnpf1 = (const float*)d_in[3];
    const float* Wpf2  = (const float*)d_in[4];
    const float* bpf2  = (const float*)d_in[5];
    const float* bnpf2 = (const float*)d_in[6];
    const float* Wc1   = (const float*)d_in[7];
    const float* bc1   = (const float*)d_in[8];
    const float* bnc1  = (const float*)d_in[9];
    const float* Wc2   = (const float*)d_in[10];
    const float* bc2   = (const float*)d_in[11];
    const float* bnc2  = (const float*)d_in[12];
    const float* Wc3   = (const float*)d_in[13];
    const float* bc3   = (const float*)d_in[14];
    const float* bnc3  = (const float*)d_in[15];
    const float* Wdf   = (const float*)d_in[16];
    const float* Wpw   = (const float*)d_in[17];
    const float* bf    = (const float*)d_in[18];
    const float* bnf   = (const float*)d_in[19];

    float*  wsf  = (float*)d_ws;
    float4* pts  = (float4*)((char*)d_ws + WS_PTS_OFF);
    int*    idxw = (int*)((char*)d_ws + WS_IDX_OFF);
    float*  dwl  = (float*)((char*)d_ws + WS_DWL_OFF);
    float*  outp = (float*)d_out;

    hipLaunchKernelGGL(bn_prep, dim3(1), dim3(1024), 0, stream,
                       bnpf1, bnpf2, bnc1, bnc2, bnc3, bnf,
                       Wpf1, bpf1, Wpf2, bpf2, wsf);
    hipLaunchKernelGGL(pack_pts, dim3((B_ * NIN_ + 255) / 256), dim3(256), 0, stream,
                       inp, pts);
    hipLaunchKernelGGL(knn_kernel, dim3((B_ * P_) / 4), dim3(256), 0, stream,
                       pts, idxw);
    hipLaunchKernelGGL(p1_kernel, dim3((B_ * P_) / 4), dim3(256), 0, stream,
                       inp, idxw, Wc1, bc1, Wc2, bc2, Wc3, bc3, Wdf, wsf,
                       dwl, outp);
    hipLaunchKernelGGL(pw_kernel, dim3((B_ * P_) / 32), dim3(256), 0, stream,
                       dwl, Wpw, bf, wsf, outp);
}

// Round 6
// 125.887 us; speedup vs baseline: 2.9398x; 1.0253x over previous
//
#include <hip/hip_runtime.h>
#include <math.h>

#define B_    8
#define NIN_  4096
#define P_    1024
#define K_    16
#define F_    64
#define CH_   67      // 3 + F
#define CPF_  64
#define CIN_  128
#define C_    128

// ---- ws float-offset layout ----
#define S_PF1  0
#define SH_PF1 64
#define S_PF2  128
#define SH_PF2 192
#define S_C1   256
#define SH_C1  512
#define S_C2   768
#define SH_C2  1024
#define S_C3   1280
#define SH_C3  1536
#define S_F    1792
#define SH_F   1920
#define M_OFF  2048     // fused pf matrix 3x64
#define C0_OFF 2240     // fused pf bias 64

// byte offsets in ws
#define WS_PTS_OFF  16384
#define WS_IDX_OFF  (WS_PTS_OFF + B_ * NIN_ * 16)          // 540672
#define WS_DWL_OFF  (WS_IDX_OFF + B_ * P_ * K_ * 4)        // 1064960

__device__ __forceinline__ float rlf(float x, int l) {
    return __int_as_float(__builtin_amdgcn_readlane(__float_as_int(x), l));
}
__device__ __forceinline__ float eluf(float z) {
    return z > 0.f ? z : expm1f(z);
}
// whole-wave shift-right-by-1 via DPP (VALU, no DS pipe). lane0 keeps old.
__device__ __forceinline__ float dpp_shr1_f(float x) {
    return __int_as_float(__builtin_amdgcn_update_dpp(
        __float_as_int(x), __float_as_int(x), 0x138, 0xF, 0xF, false));
}
__device__ __forceinline__ int dpp_shr1_i(int x) {
    return __builtin_amdgcn_update_dpp(x, x, 0x138, 0xF, 0xF, false);
}

// ---------------------------------------------------------------------------
// Kernel 0: fold BN params into scale/shift; collapse pf1+pf2 (no nonlinearity
// between them) into a single 3->64 affine (M, c0).
// ---------------------------------------------------------------------------
__global__ void bn_prep(const float* __restrict__ bn_pf1, const float* __restrict__ bn_pf2,
                        const float* __restrict__ bn_c1,  const float* __restrict__ bn_c2,
                        const float* __restrict__ bn_c3,  const float* __restrict__ bn_f,
                        const float* __restrict__ Wpf1,   const float* __restrict__ bpf1,
                        const float* __restrict__ Wpf2,   const float* __restrict__ bpf2,
                        float* __restrict__ wsf) {
    int t = threadIdx.x;
    {
        const float* src; int nch, c, so, sho;
        if (t < 64)       { src = bn_pf1; nch = 64;  c = t;        so = S_PF1; sho = SH_PF1; }
        else if (t < 128) { src = bn_pf2; nch = 64;  c = t - 64;   so = S_PF2; sho = SH_PF2; }
        else if (t < 384) { src = bn_c1;  nch = 256; c = t - 128;  so = S_C1;  sho = SH_C1; }
        else if (t < 640) { src = bn_c2;  nch = 256; c = t - 384;  so = S_C2;  sho = SH_C2; }
        else if (t < 896) { src = bn_c3;  nch = 256; c = t - 640;  so = S_C3;  sho = SH_C3; }
        else              { src = bn_f;   nch = 128; c = t - 896;  so = S_F;   sho = SH_F;  }
        float g = src[c], b = src[nch + c], m = src[2 * nch + c], v = src[3 * nch + c];
        float s = g * rsqrtf(v + 1e-3f);
        wsf[so + c]  = s;
        wsf[sho + c] = b - m * s;
    }
    __syncthreads();
    if (t < 64) {
        int o = t;
        float s2 = wsf[S_PF2 + o], t2 = wsf[SH_PF2 + o];
        float m0 = 0.f, m1 = 0.f, m2 = 0.f, cc = 0.f;
        for (int c = 0; c < 64; ++c) {
            float s1 = wsf[S_PF1 + c], t1 = wsf[SH_PF1 + c];
            float d1 = s1 * bpf1[c] + t1;
            float w2 = Wpf2[c * 64 + o];
            m0 += Wpf1[0 * 64 + c] * s1 * w2;
            m1 += Wpf1[1 * 64 + c] * s1 * w2;
            m2 += Wpf1[2 * 64 + c] * s1 * w2;
            cc += d1 * w2;
        }
        wsf[M_OFF + 0 * 64 + o] = m0 * s2;
        wsf[M_OFF + 1 * 64 + o] = m1 * s2;
        wsf[M_OFF + 2 * 64 + o] = m2 * s2;
        wsf[C0_OFF + o]         = cc * s2 + bpf2[o] * s2 + t2;
    }
}

// ---------------------------------------------------------------------------
// Kernel 0b: pack xyz + |p|^2 into float4 (pp bitwise-identical to reference)
// ---------------------------------------------------------------------------
__global__ __launch_bounds__(256) void pack_pts(const float* __restrict__ inp,
                                                float4* __restrict__ pts) {
    int i = blockIdx.x * 256 + threadIdx.x;
    if (i < B_ * NIN_) {
        const float* r = inp + (size_t)i * CH_;
        float x = r[0], y = r[1], z = r[2];
        float pp = __fadd_rn(__fadd_rn(__fmul_rn(x, x), __fmul_rn(y, y)),
                             __fmul_rn(z, z));
        pts[i] = make_float4(x, y, z, pp);
    }
}

// ---------------------------------------------------------------------------
// Kernel 1: exact KNN. One wave per query; sorted top-32 across lanes 0..31.
// Bitonic init on first 64; insertions use DPP wave_shr1 (pure VALU, no DS)
// and kth is refreshed once per 64-group (no-op inserts are harmless:
// if dc >= all bd then no lane shifts and no lane inserts).
// d2 bitwise-identical: d2 = (qq + pp) - (2*e), no FMA.
// ---------------------------------------------------------------------------
__global__ __launch_bounds__(256) void knn_kernel(const float4* __restrict__ pts,
                                                  int* __restrict__ idxo) {
    const int wid  = (blockIdx.x << 2) | (threadIdx.x >> 6);  // query id 0..8191
    const int lane = threadIdx.x & 63;
    const float4* bp = pts + ((size_t)(wid >> 10) << 12);
    const int qi = wid & 1023;

    const float4 q = bp[qi];
    const float qq = q.w;

    // ---- group 0: bitonic sort 64 candidates by (d2, idx) ascending
    float4 p = bp[lane];
    float d;
    {
        float e = __fadd_rn(__fadd_rn(__fmul_rn(q.x, p.x), __fmul_rn(q.y, p.y)),
                            __fmul_rn(q.z, p.z));
        d = __fsub_rn(__fadd_rn(qq, p.w), __fmul_rn(2.0f, e));
    }
    int ii = lane;
#pragma unroll
    for (int k = 2; k <= 64; k <<= 1) {
#pragma unroll
        for (int j = k >> 1; j > 0; j >>= 1) {
            float od = __shfl_xor(d, j);
            int   oi = __shfl_xor(ii, j);
            bool keepmin = (((lane & k) == 0) == ((lane & j) == 0));
            bool ol = (od < d) || (od == d && oi < ii);
            bool take = keepmin ? ol : !ol;
            if (take) { d = od; ii = oi; }
        }
    }
    float bd = d;      // lane s (<32): s-th smallest
    int   bi = ii;
    float kth = rlf(bd, 31);

    float4 pn = bp[64 + lane];
    for (int j0 = 64; j0 < NIN_; j0 += 64) {
        p = pn;
        if (j0 + 64 < NIN_) pn = bp[j0 + 64 + lane];
        float e  = __fadd_rn(__fadd_rn(__fmul_rn(q.x, p.x), __fmul_rn(q.y, p.y)),
                             __fmul_rn(q.z, p.z));
        float d2 = __fsub_rn(__fadd_rn(qq, p.w), __fmul_rn(2.0f, e));

        unsigned long long m = __ballot(d2 < kth);
        if (m) {
            do {
                int c = __builtin_ctzll(m);
                m &= m - 1;
                float dc = rlf(d2, c);           // uniform broadcast (VALU)
                int   ic = j0 + c;
                float prev  = dpp_shr1_f(bd);    // lane-1's value (VALU DPP)
                int   previ = dpp_shr1_i(bi);
                bool  shift = (bd > dc);         // strict: ties keep lower idx
                bool  ins   = shift && ((lane == 0) || (prev <= dc));
                if (shift) { bd = prev; bi = previ; }
                if (ins)   { bd = dc;   bi = ic;    }
            } while (m);
            kth = rlf(bd, 31);                   // refresh once per group
        }
    }

    if (lane < 32 && !(lane & 1)) {
        idxo[((size_t)wid << 4) | (lane >> 1)] = bi;
    }
}

// ---------------------------------------------------------------------------
// Kernel 2: stages A..H, TWO points per wave (halves per-point weight
// traffic: one weight load feeds both points' FMAs). 4 waves/block, no
// barriers. G-stage handled sequentially per point to bound liveness.
// ---------------------------------------------------------------------------
__global__ __launch_bounds__(256) void p1_kernel(
    const float* __restrict__ inp, const int* __restrict__ idx,
    const float* __restrict__ Wc1,  const float* __restrict__ bc1,
    const float* __restrict__ Wc2,  const float* __restrict__ bc2,
    const float* __restrict__ Wc3,  const float* __restrict__ bc3,
    const float* __restrict__ Wdf,  const float* __restrict__ wsf,
    float* __restrict__ dwl, float* __restrict__ out) {

    __shared__ float xS[4][2][256];
    __shared__ float yS[4][2][256];

    const int w   = threadIdx.x >> 6;
    const int l   = threadIdx.x & 63;
    const int ngA = blockIdx.x * 8 + w * 2;   // block spans 8 points, same batch
    const int ngB = ngA + 1;
    const int b   = ngA >> 10;
    const float* brow = inp + (size_t)b * NIN_ * CH_;
    const int* ipA = idx + (size_t)ngA * K_;
    const int* ipB = idx + (size_t)ngB * K_;

    const int nA = ngA & 1023, nB = ngB & 1023;
    const float q0A = brow[(size_t)nA * CH_ + 0];
    const float q1A = brow[(size_t)nA * CH_ + 1];
    const float q2A = brow[(size_t)nA * CH_ + 2];
    const float q0B = brow[(size_t)nB * CH_ + 0];
    const float q1B = brow[(size_t)nB * CH_ + 1];
    const float q2B = brow[(size_t)nB * CH_ + 2];

    // ---- xyz gathers: one load instr per point. lanes 0..47: k=l/3, d=l%3
    float pdA, pdB;
    {
        int k3 = (l * 21846) >> 16;
        k3 = (k3 > 15) ? 15 : k3;
        int d3 = l - ((k3 << 1) + k3);
        d3 = (d3 > 2) ? 2 : d3;
        int nblA = ipA[k3];
        int nblB = ipB[k3];
        float vA = 0.f, vB = 0.f;
        if (l < 48) {
            vA = brow[(size_t)nblA * CH_ + d3];
            vB = brow[(size_t)nblB * CH_ + d3];
        }
        float qvA = (d3 == 0) ? q0A : ((d3 == 1) ? q1A : q2A);
        float qvB = (d3 == 0) ? q0B : ((d3 == 1) ? q1B : q2B);
        pdA = vA - qvA;
        pdB = vB - qvB;
    }

    // ---- Stage D: x1[o] = BN(elu(pnb48 . Wc1 + bc1)),  o = 4l+r
    {
        float4 accA = *reinterpret_cast<const float4*>(bc1 + 4 * l);
        float4 accB = accA;
#pragma unroll 4
        for (int t4 = 0; t4 < 12; ++t4) {
            const float* wb = Wc1 + (size_t)(t4 * 4) * 256 + 4 * l;
            float4 w0 = *reinterpret_cast<const float4*>(wb);
            float4 w1 = *reinterpret_cast<const float4*>(wb + 256);
            float4 w2 = *reinterpret_cast<const float4*>(wb + 512);
            float4 w3 = *reinterpret_cast<const float4*>(wb + 768);
            float a0 = rlf(pdA, 4 * t4 + 0), a1 = rlf(pdA, 4 * t4 + 1);
            float a2 = rlf(pdA, 4 * t4 + 2), a3 = rlf(pdA, 4 * t4 + 3);
            accA.x += a0 * w0.x + a1 * w1.x + a2 * w2.x + a3 * w3.x;
            accA.y += a0 * w0.y + a1 * w1.y + a2 * w2.y + a3 * w3.y;
            accA.z += a0 * w0.z + a1 * w1.z + a2 * w2.z + a3 * w3.z;
            accA.w += a0 * w0.w + a1 * w1.w + a2 * w2.w + a3 * w3.w;
            float e0 = rlf(pdB, 4 * t4 + 0), e1 = rlf(pdB, 4 * t4 + 1);
            float e2 = rlf(pdB, 4 * t4 + 2), e3 = rlf(pdB, 4 * t4 + 3);
            accB.x += e0 * w0.x + e1 * w1.x + e2 * w2.x + e3 * w3.x;
            accB.y += e0 * w0.y + e1 * w1.y + e2 * w2.y + e3 * w3.y;
            accB.z += e0 * w0.z + e1 * w1.z + e2 * w2.z + e3 * w3.z;
            accB.w += e0 * w0.w + e1 * w1.w + e2 * w2.w + e3 * w3.w;
        }
        float4 sc = *reinterpret_cast<const float4*>(wsf + S_C1 + 4 * l);
        float4 sh = *reinterpret_cast<const float4*>(wsf + SH_C1 + 4 * l);
        float4 rA, rB;
        rA.x = sc.x * eluf(accA.x) + sh.x;  rB.x = sc.x * eluf(accB.x) + sh.x;
        rA.y = sc.y * eluf(accA.y) + sh.y;  rB.y = sc.y * eluf(accB.y) + sh.y;
        rA.z = sc.z * eluf(accA.z) + sh.z;  rB.z = sc.z * eluf(accB.z) + sh.z;
        rA.w = sc.w * eluf(accA.w) + sh.w;  rB.w = sc.w * eluf(accB.w) + sh.w;
        *reinterpret_cast<float4*>(&xS[w][0][4 * l]) = rA;
        *reinterpret_cast<float4*>(&xS[w][1][4 * l]) = rB;
    }

    // ---- Stage E: x2[o] = BN(elu(sum_w x1[w][c]*Wc2[w][o])),  c = l>>2
    {
        float4 accA = *reinterpret_cast<const float4*>(bc2 + 4 * l);
        float4 accB = accA;
        const int csel = l >> 2;
#pragma unroll 8
        for (int w16 = 0; w16 < 16; ++w16) {
            float4 w4 = *reinterpret_cast<const float4*>(Wc2 + (size_t)w16 * 256 + 4 * l);
            float xa = xS[w][0][w16 * 16 + csel];
            float xb = xS[w][1][w16 * 16 + csel];
            accA.x += xa * w4.x; accA.y += xa * w4.y;
            accA.z += xa * w4.z; accA.w += xa * w4.w;
            accB.x += xb * w4.x; accB.y += xb * w4.y;
            accB.z += xb * w4.z; accB.w += xb * w4.w;
        }
        float4 sc = *reinterpret_cast<const float4*>(wsf + S_C2 + 4 * l);
        float4 sh = *reinterpret_cast<const float4*>(wsf + SH_C2 + 4 * l);
        float4 rA, rB;
        rA.x = sc.x * eluf(accA.x) + sh.x;  rB.x = sc.x * eluf(accB.x) + sh.x;
        rA.y = sc.y * eluf(accA.y) + sh.y;  rB.y = sc.y * eluf(accB.y) + sh.y;
        rA.z = sc.z * eluf(accA.z) + sh.z;  rB.z = sc.z * eluf(accB.z) + sh.z;
        rA.w = sc.w * eluf(accA.w) + sh.w;  rB.w = sc.w * eluf(accB.w) + sh.w;
        *reinterpret_cast<float4*>(&yS[w][0][4 * l]) = rA;
        *reinterpret_cast<float4*>(&yS[w][1][4 * l]) = rB;
    }

    // ---- Stage F: x3 (kept in registers)
    float x3A[4], x3B[4];
    {
        float4 accA = *reinterpret_cast<const float4*>(bc3 + 4 * l);
        float4 accB = accA;
        const int csel = l >> 2;
#pragma unroll 8
        for (int w16 = 0; w16 < 16; ++w16) {
            float4 w4 = *reinterpret_cast<const float4*>(Wc3 + (size_t)w16 * 256 + 4 * l);
            float xa = yS[w][0][w16 * 16 + csel];
            float xb = yS[w][1][w16 * 16 + csel];
            accA.x += xa * w4.x; accA.y += xa * w4.y;
            accA.z += xa * w4.z; accA.w += xa * w4.w;
            accB.x += xb * w4.x; accB.y += xb * w4.y;
            accB.z += xb * w4.z; accB.w += xb * w4.w;
        }
        float4 sc = *reinterpret_cast<const float4*>(wsf + S_C3 + 4 * l);
        float4 sh = *reinterpret_cast<const float4*>(wsf + SH_C3 + 4 * l);
        x3A[0] = sc.x * eluf(accA.x) + sh.x;  x3B[0] = sc.x * eluf(accB.x) + sh.x;
        x3A[1] = sc.y * eluf(accA.y) + sh.y;  x3B[1] = sc.y * eluf(accB.y) + sh.y;
        x3A[2] = sc.z * eluf(accA.z) + sh.z;  x3B[2] = sc.z * eluf(accB.z) + sh.z;
        x3A[3] = sc.w * eluf(accA.w) + sh.w;  x3B[3] = sc.w * eluf(accB.w) + sh.w;
    }

    const float Mw0 = wsf[M_OFF + l];
    const float Mw1 = wsf[M_OFF + 64 + l];
    const float Mw2 = wsf[M_OFF + 128 + l];
    const float cc0 = wsf[C0_OFF + l];

    // ---- point A: fnb loads, h2, then G+H fused
    float fnbA[16];
#pragma unroll
    for (int k = 0; k < 16; ++k) {
        int nbs = __builtin_amdgcn_readfirstlane(ipA[k]);
        fnbA[k] = brow[(size_t)nbs * CH_ + 3 + l];
    }
    float h2A[16];
#pragma unroll
    for (int k = 0; k < 16; ++k) {
        float s0 = rlf(pdA, 3 * k), s1 = rlf(pdA, 3 * k + 1), s2 = rlf(pdA, 3 * k + 2);
        h2A[k] = fmaf(s0, Mw0, fmaf(s1, Mw1, fmaf(s2, Mw2, cc0)));
    }
    // issue B's fnb loads so they overlap with A's G compute
    float fnbB[16];
#pragma unroll
    for (int k = 0; k < 16; ++k) {
        int nbs = __builtin_amdgcn_readfirstlane(ipB[k]);
        fnbB[k] = brow[(size_t)nbs * CH_ + 3 + l];
    }
    {
        float d00 = 0.f, d01 = 0.f, d10 = 0.f, d11 = 0.f;
#pragma unroll 4
        for (int i = 0; i < 16; ++i) {
            float fa = 0.f, fb = 0.f;
#pragma unroll
            for (int j = 0; j < 16; ++j) {
                float xv = rlf(x3A[j & 3], i * 4 + (j >> 2));
                fa += xv * h2A[j];
                fb += xv * fnbA[j];
            }
            const float* wr = Wdf + (size_t)i * 256;
            float2 wlo = *reinterpret_cast<const float2*>(wr + 2 * l);
            float2 whi = *reinterpret_cast<const float2*>(wr + 128 + 2 * l);
            d00 += fa * wlo.x; d01 += fa * wlo.y;
            d10 += fb * whi.x; d11 += fb * whi.y;
        }
        float* drow = dwl + (size_t)ngA * 256;
        *reinterpret_cast<float2*>(drow + 2 * l)       = make_float2(d00, d01);
        *reinterpret_cast<float2*>(drow + 128 + 2 * l) = make_float2(d10, d11);
    }

    // ---- point B: h2, then G+H fused
    float h2B[16];
#pragma unroll
    for (int k = 0; k < 16; ++k) {
        float s0 = rlf(pdB, 3 * k), s1 = rlf(pdB, 3 * k + 1), s2 = rlf(pdB, 3 * k + 2);
        h2B[k] = fmaf(s0, Mw0, fmaf(s1, Mw1, fmaf(s2, Mw2, cc0)));
    }
    {
        float d00 = 0.f, d01 = 0.f, d10 = 0.f, d11 = 0.f;
#pragma unroll 4
        for (int i = 0; i < 16; ++i) {
            float fa = 0.f, fb = 0.f;
#pragma unroll
            for (int j = 0; j < 16; ++j) {
                float xv = rlf(x3B[j & 3], i * 4 + (j >> 2));
                fa += xv * h2B[j];
                fb += xv * fnbB[j];
            }
            const float* wr = Wdf + (size_t)i * 256;
            float2 wlo = *reinterpret_cast<const float2*>(wr + 2 * l);
            float2 whi = *reinterpret_cast<const float2*>(wr + 128 + 2 * l);
            d00 += fa * wlo.x; d01 += fa * wlo.y;
            d10 += fb * whi.x; d11 += fb * whi.y;
        }
        float* drow = dwl + (size_t)ngB * 256;
        *reinterpret_cast<float2*>(drow + 2 * l)       = make_float2(d00, d01);
        *reinterpret_cast<float2*>(drow + 128 + 2 * l) = make_float2(d10, d11);
    }

    if (l < 3) {
        out[(size_t)ngA * 131 + l] = (l == 0) ? q0A : ((l == 1) ? q1A : q2A);
        out[(size_t)ngB * 131 + l] = (l == 0) ? q0B : ((l == 1) ? q1B : q2B);
    }
}

// ---------------------------------------------------------------------------
// Kernel 3: final pointwise layer as tiled f32 GEMM: M=8192 K=256 N=128.
// ---------------------------------------------------------------------------
__global__ __launch_bounds__(256) void pw_kernel(const float* __restrict__ dwl,
                                                 const float* __restrict__ Wpw,
                                                 const float* __restrict__ bf,
                                                 const float* __restrict__ wsf,
                                                 float* __restrict__ out) {
    __shared__ float As[32][256];
    const int tid = threadIdx.x;
    const int m0  = blockIdx.x * 32;

#pragma unroll
    for (int i = 0; i < 8; ++i) {
        int fi  = i * 1024 + tid * 4;
        int row = fi >> 8, col = fi & 255;
        *reinterpret_cast<float4*>(&As[row][col]) =
            *reinterpret_cast<const float4*>(dwl + (size_t)(m0 + row) * 256 + col);
    }
    __syncthreads();

    const int mq = tid >> 5;          // 8 m-quads
    const int nq = tid & 31;          // 32 n-quads
    float acc[4][4];
#pragma unroll
    for (int mi = 0; mi < 4; ++mi)
#pragma unroll
        for (int ni = 0; ni < 4; ++ni) acc[mi][ni] = 0.f;

#pragma unroll 4
    for (int k4 = 0; k4 < 64; ++k4) {
        float4 a[4], bw[4];
#pragma unroll
        for (int mi = 0; mi < 4; ++mi)
            a[mi] = *reinterpret_cast<const float4*>(&As[mq * 4 + mi][k4 * 4]);
#pragma unroll
        for (int ki = 0; ki < 4; ++ki)
            bw[ki] = *reinterpret_cast<const float4*>(Wpw + (size_t)(k4 * 4 + ki) * 128 + nq * 4);
#pragma unroll
        for (int mi = 0; mi < 4; ++mi) {
            const float4 am = a[mi];
            acc[mi][0] += am.x * bw[0].x + am.y * bw[1].x + am.z * bw[2].x + am.w * bw[3].x;
            acc[mi][1] += am.x * bw[0].y + am.y * bw[1].y + am.z * bw[2].y + am.w * bw[3].y;
            acc[mi][2] += am.x * bw[0].z + am.y * bw[1].z + am.z * bw[2].z + am.w * bw[3].z;
            acc[mi][3] += am.x * bw[0].w + am.y * bw[1].w + am.z * bw[2].w + am.w * bw[3].w;
        }
    }

    float4 b4  = *reinterpret_cast<const float4*>(bf + nq * 4);
    float4 sc4 = *reinterpret_cast<const float4*>(wsf + S_F + nq * 4);
    float4 sh4 = *reinterpret_cast<const float4*>(wsf + SH_F + nq * 4);
#pragma unroll
    for (int mi = 0; mi < 4; ++mi) {
        const int m = m0 + mq * 4 + mi;
        float* orow = out + (size_t)m * 131 + 3 + nq * 4;
        orow[0] = sc4.x * eluf(acc[mi][0] + b4.x) + sh4.x;
        orow[1] = sc4.y * eluf(acc[mi][1] + b4.y) + sh4.y;
        orow[2] = sc4.z * eluf(acc[mi][2] + b4.z) + sh4.z;
        orow[3] = sc4.w * eluf(acc[mi][3] + b4.w) + sh4.w;
    }
}

// ---------------------------------------------------------------------------
extern "C" void kernel_launch(void* const* d_in, const int* in_sizes, int n_in,
                              void* d_out, int out_size, void* d_ws, size_t ws_size,
                              hipStream_t stream) {
    const float* inp   = (const float*)d_in[0];
    const float* Wpf1  = (const float*)d_in[1];
    const float* bpf1  = (const float*)d_in[2];
    const float* bnpf1 = (const float*)d_in[3];
    const float* Wpf2  = (const float*)d_in[4];
    const float* bpf2  = (const float*)d_in[5];
    const float* bnpf2 = (const float*)d_in[6];
    const float* Wc1   = (const float*)d_in[7];
    const float* bc1   = (const float*)d_in[8];
    const float* bnc1  = (const float*)d_in[9];
    const float* Wc2   = (const float*)d_in[10];
    const float* bc2   = (const float*)d_in[11];
    const float* bnc2  = (const float*)d_in[12];
    const float* Wc3   = (const float*)d_in[13];
    const float* bc3   = (const float*)d_in[14];
    const float* bnc3  = (const float*)d_in[15];
    const float* Wdf   = (const float*)d_in[16];
    const float* Wpw   = (const float*)d_in[17];
    const float* bf    = (const float*)d_in[18];
    const float* bnf   = (const float*)d_in[19];

    float*  wsf  = (float*)d_ws;
    float4* pts  = (float4*)((char*)d_ws + WS_PTS_OFF);
    int*    idxw = (int*)((char*)d_ws + WS_IDX_OFF);
    float*  dwl  = (float*)((char*)d_ws + WS_DWL_OFF);
    float*  outp = (float*)d_out;

    hipLaunchKernelGGL(bn_prep, dim3(1), dim3(1024), 0, stream,
                       bnpf1, bnpf2, bnc1, bnc2, bnc3, bnf,
                       Wpf1, bpf1, Wpf2, bpf2, wsf);
    hipLaunchKernelGGL(pack_pts, dim3((B_ * NIN_ + 255) / 256), dim3(256), 0, stream,
                       inp, pts);
    hipLaunchKernelGGL(knn_kernel, dim3((B_ * P_) / 4), dim3(256), 0, stream,
                       pts, idxw);
    hipLaunchKernelGGL(p1_kernel, dim3((B_ * P_) / 8), dim3(256), 0, stream,
                       inp, idxw, Wc1, bc1, Wc2, bc2, Wc3, bc3, Wdf, wsf,
                       dwl, outp);
    hipLaunchKernelGGL(pw_kernel, dim3((B_ * P_) / 32), dim3(256), 0, stream,
                       dwl, Wpw, bf, wsf, outp);
}

// Round 7
// 125.489 us; speedup vs baseline: 2.9491x; 1.0032x over previous
//
#include <hip/hip_runtime.h>
#include <math.h>

#define B_    8
#define NIN_  4096
#define P_    1024
#define K_    16
#define F_    64
#define CH_   67      // 3 + F
#define CPF_  64
#define CIN_  128
#define C_    128

// ---- ws float-offset layout ----
#define S_PF1  0
#define SH_PF1 64
#define S_PF2  128
#define SH_PF2 192
#define S_C1   256
#define SH_C1  512
#define S_C2   768
#define SH_C2  1024
#define S_C3   1280
#define SH_C3  1536
#define S_F    1792
#define SH_F   1920
#define M_OFF  2048     // fused pf matrix 3x64
#define C0_OFF 2240     // fused pf bias 64

// byte offsets in ws
#define WS_PTS_OFF  16384
#define WS_IDX_OFF  (WS_PTS_OFF + B_ * NIN_ * 16)          // 540672
#define WS_DWL_OFF  (WS_IDX_OFF + B_ * P_ * K_ * 4)        // 1064960

__device__ __forceinline__ float rlf(float x, int l) {
    return __int_as_float(__builtin_amdgcn_readlane(__float_as_int(x), l));
}
__device__ __forceinline__ float eluf(float z) {
    return z > 0.f ? z : expm1f(z);
}
// whole-wave shift-right-by-1 via DPP (VALU). lane0 receives -inf.
__device__ __forceinline__ float dpp_shr1_ninf(float x) {
    return __int_as_float(__builtin_amdgcn_update_dpp(
        (int)0xFF800000, __float_as_int(x), 0x138, 0xF, 0xF, false));
}
// lane0 keeps old value (don't-care for index path)
__device__ __forceinline__ int dpp_shr1_i(int x) {
    return __builtin_amdgcn_update_dpp(x, x, 0x138, 0xF, 0xF, false);
}

// ---------------------------------------------------------------------------
// Kernel 0 (fused): blocks 0..127 pack xyz+|p|^2 into float4;
// block 128 folds BN params and collapses pf1+pf2 into a 3->64 affine.
// ---------------------------------------------------------------------------
__global__ __launch_bounds__(256) void prep_kernel(
    const float* __restrict__ inp, float4* __restrict__ pts,
    const float* __restrict__ bn_pf1, const float* __restrict__ bn_pf2,
    const float* __restrict__ bn_c1,  const float* __restrict__ bn_c2,
    const float* __restrict__ bn_c3,  const float* __restrict__ bn_f,
    const float* __restrict__ Wpf1,   const float* __restrict__ bpf1,
    const float* __restrict__ Wpf2,   const float* __restrict__ bpf2,
    float* __restrict__ wsf) {
    const int tid = threadIdx.x;
    if (blockIdx.x < 128) {
        int i = blockIdx.x * 256 + tid;
        const float* r = inp + (size_t)i * CH_;
        float x = r[0], y = r[1], z = r[2];
        float pp = __fadd_rn(__fadd_rn(__fmul_rn(x, x), __fmul_rn(y, y)),
                             __fmul_rn(z, z));
        pts[i] = make_float4(x, y, z, pp);
        return;
    }
    // ---- BN fold (1024 logical slots on 256 threads) ----
#pragma unroll
    for (int it = 0; it < 4; ++it) {
        int t = it * 256 + tid;
        const float* src; int nch, c, so, sho;
        if (t < 64)       { src = bn_pf1; nch = 64;  c = t;        so = S_PF1; sho = SH_PF1; }
        else if (t < 128) { src = bn_pf2; nch = 64;  c = t - 64;   so = S_PF2; sho = SH_PF2; }
        else if (t < 384) { src = bn_c1;  nch = 256; c = t - 128;  so = S_C1;  sho = SH_C1; }
        else if (t < 640) { src = bn_c2;  nch = 256; c = t - 384;  so = S_C2;  sho = SH_C2; }
        else if (t < 896) { src = bn_c3;  nch = 256; c = t - 640;  so = S_C3;  sho = SH_C3; }
        else              { src = bn_f;   nch = 128; c = t - 896;  so = S_F;   sho = SH_F;  }
        float g = src[c], b = src[nch + c], m = src[2 * nch + c], v = src[3 * nch + c];
        float s = g * rsqrtf(v + 1e-3f);
        wsf[so + c]  = s;
        wsf[sho + c] = b - m * s;
    }
    __syncthreads();
    if (tid < 64) {
        int o = tid;
        float s2 = wsf[S_PF2 + o], t2 = wsf[SH_PF2 + o];
        float m0 = 0.f, m1 = 0.f, m2 = 0.f, cc = 0.f;
        for (int c = 0; c < 64; ++c) {
            float s1 = wsf[S_PF1 + c], t1 = wsf[SH_PF1 + c];
            float d1 = s1 * bpf1[c] + t1;
            float w2 = Wpf2[c * 64 + o];
            m0 += Wpf1[0 * 64 + c] * s1 * w2;
            m1 += Wpf1[1 * 64 + c] * s1 * w2;
            m2 += Wpf1[2 * 64 + c] * s1 * w2;
            cc += d1 * w2;
        }
        wsf[M_OFF + 0 * 64 + o] = m0 * s2;
        wsf[M_OFF + 1 * 64 + o] = m1 * s2;
        wsf[M_OFF + 2 * 64 + o] = m2 * s2;
        wsf[C0_OFF + o]         = cc * s2 + bpf2[o] * s2 + t2;
    }
}

// ---------------------------------------------------------------------------
// Kernel 1: exact KNN. One wave per query; sorted top-32 across lanes 0..31.
// Bitonic init on first 64; stream in 128-candidate batches (2-deep
// prefetch). Insert uses the sorted-insert identity:
//   new_bd = min(bd, max(prev, dc))   with prev(lane0) = -inf
//   new_bi = (bd>dc) ? ((prev>dc) ? previ : ic) : bi
// which is exactly strict-shift insertion (ties keep lower index first).
// d2 bitwise-identical to reference: d2 = (qq + pp) - (2*e), no FMA.
// ---------------------------------------------------------------------------
__global__ __launch_bounds__(256) void knn_kernel(const float4* __restrict__ pts,
                                                  int* __restrict__ idxo) {
    const int wid  = (blockIdx.x << 2) | (threadIdx.x >> 6);  // query id 0..8191
    const int lane = threadIdx.x & 63;
    const float4* bp = pts + ((size_t)(wid >> 10) << 12);
    const int qi = wid & 1023;

    const float4 q = bp[qi];
    const float qq = q.w;

#define DIST2(P) __fsub_rn(__fadd_rn(qq, (P).w), __fmul_rn(2.0f, \
    __fadd_rn(__fadd_rn(__fmul_rn(q.x, (P).x), __fmul_rn(q.y, (P).y)), \
              __fmul_rn(q.z, (P).z))))

    // issue upcoming candidate loads early so they overlap the bootstrap sort
    float4 p  = bp[lane];
    float4 g1 = bp[64 + lane];
    float4 g2 = bp[128 + lane];
    float4 g3 = bp[192 + lane];

    // ---- bootstrap: bitonic sort first 64 by (d2, idx) ascending
    float d = DIST2(p);
    int ii = lane;
#pragma unroll
    for (int k = 2; k <= 64; k <<= 1) {
#pragma unroll
        for (int j = k >> 1; j > 0; j >>= 1) {
            float od = __shfl_xor(d, j);
            int   oi = __shfl_xor(ii, j);
            bool keepmin = (((lane & k) == 0) == ((lane & j) == 0));
            bool ol = (od < d) || (od == d && oi < ii);
            bool take = keepmin ? ol : !ol;
            if (take) { d = od; ii = oi; }
        }
    }
    float bd = d;      // lane s (<32): s-th smallest
    int   bi = ii;
    float kth = rlf(bd, 31);

#define INS_LOOP(MV, D2V, BASE)                                        \
    if (MV) {                                                          \
        do {                                                           \
            int c = (int)__builtin_ctzll(MV); MV &= MV - 1;            \
            float dc = rlf(D2V, c);                                    \
            int   ic = (BASE) + c;                                     \
            float prev  = dpp_shr1_ninf(bd);                           \
            int   previ = dpp_shr1_i(bi);                              \
            bool c1 = (bd > dc);                                       \
            bool c2 = (prev > dc);                                     \
            bd = fminf(bd, fmaxf(prev, dc));                           \
            bi = c1 ? (c2 ? previ : ic) : bi;                          \
        } while (MV);                                                  \
        kth = rlf(bd, 31);                                             \
    }

    // ---- single group at j0 = 64
    {
        float d2 = DIST2(g1);
        unsigned long long m = __ballot(d2 < kth);
        INS_LOOP(m, d2, 64);
    }

    // ---- main loop: 31 iterations x 128 candidates, 2-deep prefetch
    for (int j0 = 128; j0 < NIN_; j0 += 128) {
        float4 pa = g2, pb = g3;
        int jn = j0 + 128;
        if (jn < NIN_) { g2 = bp[jn + lane]; g3 = bp[jn + 64 + lane]; }
        float d2a = DIST2(pa);
        unsigned long long ma = __ballot(d2a < kth);
        INS_LOOP(ma, d2a, j0);
        float d2b = DIST2(pb);
        unsigned long long mb = __ballot(d2b < kth);
        INS_LOOP(mb, d2b, j0 + 64);
    }
#undef INS_LOOP
#undef DIST2

    if (lane < 32 && !(lane & 1)) {
        idxo[((size_t)wid << 4) | (lane >> 1)] = bi;
    }
}

// ---------------------------------------------------------------------------
// Kernel 2: stages A..H, TWO points per wave (halves per-point weight
// traffic: one weight load feeds both points' FMAs). 4 waves/block, no
// barriers. G-stage handled sequentially per point to bound liveness.
// ---------------------------------------------------------------------------
__global__ __launch_bounds__(256) void p1_kernel(
    const float* __restrict__ inp, const int* __restrict__ idx,
    const float* __restrict__ Wc1,  const float* __restrict__ bc1,
    const float* __restrict__ Wc2,  const float* __restrict__ bc2,
    const float* __restrict__ Wc3,  const float* __restrict__ bc3,
    const float* __restrict__ Wdf,  const float* __restrict__ wsf,
    float* __restrict__ dwl, float* __restrict__ out) {

    __shared__ float xS[4][2][256];
    __shared__ float yS[4][2][256];

    const int w   = threadIdx.x >> 6;
    const int l   = threadIdx.x & 63;
    const int ngA = blockIdx.x * 8 + w * 2;   // block spans 8 points, same batch
    const int ngB = ngA + 1;
    const int b   = ngA >> 10;
    const float* brow = inp + (size_t)b * NIN_ * CH_;
    const int* ipA = idx + (size_t)ngA * K_;
    const int* ipB = idx + (size_t)ngB * K_;

    const int nA = ngA & 1023, nB = ngB & 1023;
    const float q0A = brow[(size_t)nA * CH_ + 0];
    const float q1A = brow[(size_t)nA * CH_ + 1];
    const float q2A = brow[(size_t)nA * CH_ + 2];
    const float q0B = brow[(size_t)nB * CH_ + 0];
    const float q1B = brow[(size_t)nB * CH_ + 1];
    const float q2B = brow[(size_t)nB * CH_ + 2];

    // ---- xyz gathers: one load instr per point. lanes 0..47: k=l/3, d=l%3
    float pdA, pdB;
    {
        int k3 = (l * 21846) >> 16;
        k3 = (k3 > 15) ? 15 : k3;
        int d3 = l - ((k3 << 1) + k3);
        d3 = (d3 > 2) ? 2 : d3;
        int nblA = ipA[k3];
        int nblB = ipB[k3];
        float vA = 0.f, vB = 0.f;
        if (l < 48) {
            vA = brow[(size_t)nblA * CH_ + d3];
            vB = brow[(size_t)nblB * CH_ + d3];
        }
        float qvA = (d3 == 0) ? q0A : ((d3 == 1) ? q1A : q2A);
        float qvB = (d3 == 0) ? q0B : ((d3 == 1) ? q1B : q2B);
        pdA = vA - qvA;
        pdB = vB - qvB;
    }

    // ---- Stage D: x1[o] = BN(elu(pnb48 . Wc1 + bc1)),  o = 4l+r
    {
        float4 accA = *reinterpret_cast<const float4*>(bc1 + 4 * l);
        float4 accB = accA;
#pragma unroll 4
        for (int t4 = 0; t4 < 12; ++t4) {
            const float* wb = Wc1 + (size_t)(t4 * 4) * 256 + 4 * l;
            float4 w0 = *reinterpret_cast<const float4*>(wb);
            float4 w1 = *reinterpret_cast<const float4*>(wb + 256);
            float4 w2 = *reinterpret_cast<const float4*>(wb + 512);
            float4 w3 = *reinterpret_cast<const float4*>(wb + 768);
            float a0 = rlf(pdA, 4 * t4 + 0), a1 = rlf(pdA, 4 * t4 + 1);
            float a2 = rlf(pdA, 4 * t4 + 2), a3 = rlf(pdA, 4 * t4 + 3);
            accA.x += a0 * w0.x + a1 * w1.x + a2 * w2.x + a3 * w3.x;
            accA.y += a0 * w0.y + a1 * w1.y + a2 * w2.y + a3 * w3.y;
            accA.z += a0 * w0.z + a1 * w1.z + a2 * w2.z + a3 * w3.z;
            accA.w += a0 * w0.w + a1 * w1.w + a2 * w2.w + a3 * w3.w;
            float e0 = rlf(pdB, 4 * t4 + 0), e1 = rlf(pdB, 4 * t4 + 1);
            float e2 = rlf(pdB, 4 * t4 + 2), e3 = rlf(pdB, 4 * t4 + 3);
            accB.x += e0 * w0.x + e1 * w1.x + e2 * w2.x + e3 * w3.x;
            accB.y += e0 * w0.y + e1 * w1.y + e2 * w2.y + e3 * w3.y;
            accB.z += e0 * w0.z + e1 * w1.z + e2 * w2.z + e3 * w3.z;
            accB.w += e0 * w0.w + e1 * w1.w + e2 * w2.w + e3 * w3.w;
        }
        float4 sc = *reinterpret_cast<const float4*>(wsf + S_C1 + 4 * l);
        float4 sh = *reinterpret_cast<const float4*>(wsf + SH_C1 + 4 * l);
        float4 rA, rB;
        rA.x = sc.x * eluf(accA.x) + sh.x;  rB.x = sc.x * eluf(accB.x) + sh.x;
        rA.y = sc.y * eluf(accA.y) + sh.y;  rB.y = sc.y * eluf(accB.y) + sh.y;
        rA.z = sc.z * eluf(accA.z) + sh.z;  rB.z = sc.z * eluf(accB.z) + sh.z;
        rA.w = sc.w * eluf(accA.w) + sh.w;  rB.w = sc.w * eluf(accB.w) + sh.w;
        *reinterpret_cast<float4*>(&xS[w][0][4 * l]) = rA;
        *reinterpret_cast<float4*>(&xS[w][1][4 * l]) = rB;
    }

    // ---- Stage E: x2[o] = BN(elu(sum_w x1[w][c]*Wc2[w][o])),  c = l>>2
    {
        float4 accA = *reinterpret_cast<const float4*>(bc2 + 4 * l);
        float4 accB = accA;
        const int csel = l >> 2;
#pragma unroll 8
        for (int w16 = 0; w16 < 16; ++w16) {
            float4 w4 = *reinterpret_cast<const float4*>(Wc2 + (size_t)w16 * 256 + 4 * l);
            float xa = xS[w][0][w16 * 16 + csel];
            float xb = xS[w][1][w16 * 16 + csel];
            accA.x += xa * w4.x; accA.y += xa * w4.y;
            accA.z += xa * w4.z; accA.w += xa * w4.w;
            accB.x += xb * w4.x; accB.y += xb * w4.y;
            accB.z += xb * w4.z; accB.w += xb * w4.w;
        }
        float4 sc = *reinterpret_cast<const float4*>(wsf + S_C2 + 4 * l);
        float4 sh = *reinterpret_cast<const float4*>(wsf + SH_C2 + 4 * l);
        float4 rA, rB;
        rA.x = sc.x * eluf(accA.x) + sh.x;  rB.x = sc.x * eluf(accB.x) + sh.x;
        rA.y = sc.y * eluf(accA.y) + sh.y;  rB.y = sc.y * eluf(accB.y) + sh.y;
        rA.z = sc.z * eluf(accA.z) + sh.z;  rB.z = sc.z * eluf(accB.z) + sh.z;
        rA.w = sc.w * eluf(accA.w) + sh.w;  rB.w = sc.w * eluf(accB.w) + sh.w;
        *reinterpret_cast<float4*>(&yS[w][0][4 * l]) = rA;
        *reinterpret_cast<float4*>(&yS[w][1][4 * l]) = rB;
    }

    // ---- Stage F: x3 (kept in registers)
    float x3A[4], x3B[4];
    {
        float4 accA = *reinterpret_cast<const float4*>(bc3 + 4 * l);
        float4 accB = accA;
        const int csel = l >> 2;
#pragma unroll 8
        for (int w16 = 0; w16 < 16; ++w16) {
            float4 w4 = *reinterpret_cast<const float4*>(Wc3 + (size_t)w16 * 256 + 4 * l);
            float xa = yS[w][0][w16 * 16 + csel];
            float xb = yS[w][1][w16 * 16 + csel];
            accA.x += xa * w4.x; accA.y += xa * w4.y;
            accA.z += xa * w4.z; accA.w += xa * w4.w;
            accB.x += xb * w4.x; accB.y += xb * w4.y;
            accB.z += xb * w4.z; accB.w += xb * w4.w;
        }
        float4 sc = *reinterpret_cast<const float4*>(wsf + S_C3 + 4 * l);
        float4 sh = *reinterpret_cast<const float4*>(wsf + SH_C3 + 4 * l);
        x3A[0] = sc.x * eluf(accA.x) + sh.x;  x3B[0] = sc.x * eluf(accB.x) + sh.x;
        x3A[1] = sc.y * eluf(accA.y) + sh.y;  x3B[1] = sc.y * eluf(accB.y) + sh.y;
        x3A[2] = sc.z * eluf(accA.z) + sh.z;  x3B[2] = sc.z * eluf(accB.z) + sh.z;
        x3A[3] = sc.w * eluf(accA.w) + sh.w;  x3B[3] = sc.w * eluf(accB.w) + sh.w;
    }

    const float Mw0 = wsf[M_OFF + l];
    const float Mw1 = wsf[M_OFF + 64 + l];
    const float Mw2 = wsf[M_OFF + 128 + l];
    const float cc0 = wsf[C0_OFF + l];

    // ---- point A: fnb loads, h2, then G+H fused
    float fnbA[16];
#pragma unroll
    for (int k = 0; k < 16; ++k) {
        int nbs = __builtin_amdgcn_readfirstlane(ipA[k]);
        fnbA[k] = brow[(size_t)nbs * CH_ + 3 + l];
    }
    float h2A[16];
#pragma unroll
    for (int k = 0; k < 16; ++k) {
        float s0 = rlf(pdA, 3 * k), s1 = rlf(pdA, 3 * k + 1), s2 = rlf(pdA, 3 * k + 2);
        h2A[k] = fmaf(s0, Mw0, fmaf(s1, Mw1, fmaf(s2, Mw2, cc0)));
    }
    // issue B's fnb loads so they overlap with A's G compute
    float fnbB[16];
#pragma unroll
    for (int k = 0; k < 16; ++k) {
        int nbs = __builtin_amdgcn_readfirstlane(ipB[k]);
        fnbB[k] = brow[(size_t)nbs * CH_ + 3 + l];
    }
    {
        float d00 = 0.f, d01 = 0.f, d10 = 0.f, d11 = 0.f;
#pragma unroll 4
        for (int i = 0; i < 16; ++i) {
            float fa = 0.f, fb = 0.f;
#pragma unroll
            for (int j = 0; j < 16; ++j) {
                float xv = rlf(x3A[j & 3], i * 4 + (j >> 2));
                fa += xv * h2A[j];
                fb += xv * fnbA[j];
            }
            const float* wr = Wdf + (size_t)i * 256;
            float2 wlo = *reinterpret_cast<const float2*>(wr + 2 * l);
            float2 whi = *reinterpret_cast<const float2*>(wr + 128 + 2 * l);
            d00 += fa * wlo.x; d01 += fa * wlo.y;
            d10 += fb * whi.x; d11 += fb * whi.y;
        }
        float* drow = dwl + (size_t)ngA * 256;
        *reinterpret_cast<float2*>(drow + 2 * l)       = make_float2(d00, d01);
        *reinterpret_cast<float2*>(drow + 128 + 2 * l) = make_float2(d10, d11);
    }

    // ---- point B: h2, then G+H fused
    float h2B[16];
#pragma unroll
    for (int k = 0; k < 16; ++k) {
        float s0 = rlf(pdB, 3 * k), s1 = rlf(pdB, 3 * k + 1), s2 = rlf(pdB, 3 * k + 2);
        h2B[k] = fmaf(s0, Mw0, fmaf(s1, Mw1, fmaf(s2, Mw2, cc0)));
    }
    {
        float d00 = 0.f, d01 = 0.f, d10 = 0.f, d11 = 0.f;
#pragma unroll 4
        for (int i = 0; i < 16; ++i) {
            float fa = 0.f, fb = 0.f;
#pragma unroll
            for (int j = 0; j < 16; ++j) {
                float xv = rlf(x3B[j & 3], i * 4 + (j >> 2));
                fa += xv * h2B[j];
                fb += xv * fnbB[j];
            }
            const float* wr = Wdf + (size_t)i * 256;
            float2 wlo = *reinterpret_cast<const float2*>(wr + 2 * l);
            float2 whi = *reinterpret_cast<const float2*>(wr + 128 + 2 * l);
            d00 += fa * wlo.x; d01 += fa * wlo.y;
            d10 += fb * whi.x; d11 += fb * whi.y;
        }
        float* drow = dwl + (size_t)ngB * 256;
        *reinterpret_cast<float2*>(drow + 2 * l)       = make_float2(d00, d01);
        *reinterpret_cast<float2*>(drow + 128 + 2 * l) = make_float2(d10, d11);
    }

    if (l < 3) {
        out[(size_t)ngA * 131 + l] = (l == 0) ? q0A : ((l == 1) ? q1A : q2A);
        out[(size_t)ngB * 131 + l] = (l == 0) ? q0B : ((l == 1) ? q1B : q2B);
    }
}

// ---------------------------------------------------------------------------
// Kernel 3: final pointwise layer as tiled f32 GEMM: M=8192 K=256 N=128.
// ---------------------------------------------------------------------------
__global__ __launch_bounds__(256) void pw_kernel(const float* __restrict__ dwl,
                                                 const float* __restrict__ Wpw,
                                                 const float* __restrict__ bf,
                                                 const float* __restrict__ wsf,
                                                 float* __restrict__ out) {
    __shared__ float As[32][256];
    const int tid = threadIdx.x;
    const int m0  = blockIdx.x * 32;

#pragma unroll
    for (int i = 0; i < 8; ++i) {
        int fi  = i * 1024 + tid * 4;
        int row = fi >> 8, col = fi & 255;
        *reinterpret_cast<float4*>(&As[row][col]) =
            *reinterpret_cast<const float4*>(dwl + (size_t)(m0 + row) * 256 + col);
    }
    __syncthreads();

    const int mq = tid >> 5;          // 8 m-quads
    const int nq = tid & 31;          // 32 n-quads
    float acc[4][4];
#pragma unroll
    for (int mi = 0; mi < 4; ++mi)
#pragma unroll
        for (int ni = 0; ni < 4; ++ni) acc[mi][ni] = 0.f;

#pragma unroll 4
    for (int k4 = 0; k4 < 64; ++k4) {
        float4 a[4], bw[4];
#pragma unroll
        for (int mi = 0; mi < 4; ++mi)
            a[mi] = *reinterpret_cast<const float4*>(&As[mq * 4 + mi][k4 * 4]);
#pragma unroll
        for (int ki = 0; ki < 4; ++ki)
            bw[ki] = *reinterpret_cast<const float4*>(Wpw + (size_t)(k4 * 4 + ki) * 128 + nq * 4);
#pragma unroll
        for (int mi = 0; mi < 4; ++mi) {
            const float4 am = a[mi];
            acc[mi][0] += am.x * bw[0].x + am.y * bw[1].x + am.z * bw[2].x + am.w * bw[3].x;
            acc[mi][1] += am.x * bw[0].y + am.y * bw[1].y + am.z * bw[2].y + am.w * bw[3].y;
            acc[mi][2] += am.x * bw[0].z + am.y * bw[1].z + am.z * bw[2].z + am.w * bw[3].z;
            acc[mi][3] += am.x * bw[0].w + am.y * bw[1].w + am.z * bw[2].w + am.w * bw[3].w;
        }
    }

    float4 b4  = *reinterpret_cast<const float4*>(bf + nq * 4);
    float4 sc4 = *reinterpret_cast<const float4*>(wsf + S_F + nq * 4);
    float4 sh4 = *reinterpret_cast<const float4*>(wsf + SH_F + nq * 4);
#pragma unroll
    for (int mi = 0; mi < 4; ++mi) {
        const int m = m0 + mq * 4 + mi;
        float* orow = out + (size_t)m * 131 + 3 + nq * 4;
        orow[0] = sc4.x * eluf(acc[mi][0] + b4.x) + sh4.x;
        orow[1] = sc4.y * eluf(acc[mi][1] + b4.y) + sh4.y;
        orow[2] = sc4.z * eluf(acc[mi][2] + b4.z) + sh4.z;
        orow[3] = sc4.w * eluf(acc[mi][3] + b4.w) + sh4.w;
    }
}

// ---------------------------------------------------------------------------
extern "C" void kernel_launch(void* const* d_in, const int* in_sizes, int n_in,
                              void* d_out, int out_size, void* d_ws, size_t ws_size,
                              hipStream_t stream) {
    const float* inp   = (const float*)d_in[0];
    const float* Wpf1  = (const float*)d_in[1];
    const float* bpf1  = (const float*)d_in[2];
    const float* bnpf1 = (const float*)d_in[3];
    const float* Wpf2  = (const float*)d_in[4];
    const float* bpf2  = (const float*)d_in[5];
    const float* bnpf2 = (const float*)d_in[6];
    const float* Wc1   = (const float*)d_in[7];
    const float* bc1   = (const float*)d_in[8];
    const float* bnc1  = (const float*)d_in[9];
    const float* Wc2   = (const float*)d_in[10];
    const float* bc2   = (const float*)d_in[11];
    const float* bnc2  = (const float*)d_in[12];
    const float* Wc3   = (const float*)d_in[13];
    const float* bc3   = (const float*)d_in[14];
    const float* bnc3  = (const float*)d_in[15];
    const float* Wdf   = (const float*)d_in[16];
    const float* Wpw   = (const float*)d_in[17];
    const float* bf    = (const float*)d_in[18];
    const float* bnf   = (const float*)d_in[19];

    float*  wsf  = (float*)d_ws;
    float4* pts  = (float4*)((char*)d_ws + WS_PTS_OFF);
    int*    idxw = (int*)((char*)d_ws + WS_IDX_OFF);
    float*  dwl  = (float*)((char*)d_ws + WS_DWL_OFF);
    float*  outp = (float*)d_out;

    hipLaunchKernelGGL(prep_kernel, dim3(129), dim3(256), 0, stream,
                       inp, pts, bnpf1, bnpf2, bnc1, bnc2, bnc3, bnf,
                       Wpf1, bpf1, Wpf2, bpf2, wsf);
    hipLaunchKernelGGL(knn_kernel, dim3((B_ * P_) / 4), dim3(256), 0, stream,
                       pts, idxw);
    hipLaunchKernelGGL(p1_kernel, dim3((B_ * P_) / 8), dim3(256), 0, stream,
                       inp, idxw, Wc1, bc1, Wc2, bc2, Wc3, bc3, Wdf, wsf,
                       dwl, outp);
    hipLaunchKernelGGL(pw_kernel, dim3((B_ * P_) / 32), dim3(256), 0, stream,
                       dwl, Wpw, bf, wsf, outp);
}

// Round 8
// 121.474 us; speedup vs baseline: 3.0466x; 1.0331x over previous
//
#include <hip/hip_runtime.h>
#include <math.h>

#define B_    8
#define NIN_  4096
#define P_    1024
#define K_    16
#define F_    64
#define CH_   67      // 3 + F
#define CPF_  64
#define CIN_  128
#define C_    128

// ---- ws float-offset layout ----
#define S_PF1  0
#define SH_PF1 64
#define S_PF2  128
#define SH_PF2 192
#define S_C1   256
#define SH_C1  512
#define S_C2   768
#define SH_C2  1024
#define S_C3   1280
#define SH_C3  1536
#define S_F    1792
#define SH_F   1920
#define M_OFF  2048     // fused pf matrix 3x64
#define C0_OFF 2240     // fused pf bias 64

// byte offsets in ws
#define WS_PTS_OFF  16384
#define WS_DWL_OFF  (WS_PTS_OFF + B_ * NIN_ * 16)          // 540672

__device__ __forceinline__ float rlf(float x, int l) {
    return __int_as_float(__builtin_amdgcn_readlane(__float_as_int(x), l));
}
__device__ __forceinline__ int rli(int x, int l) {
    return __builtin_amdgcn_readlane(x, l);
}
__device__ __forceinline__ float eluf(float z) {
    return z > 0.f ? z : expm1f(z);
}
// whole-wave shift-right-by-1 via DPP (VALU). lane0 receives -inf.
__device__ __forceinline__ float dpp_shr1_ninf(float x) {
    return __int_as_float(__builtin_amdgcn_update_dpp(
        (int)0xFF800000, __float_as_int(x), 0x138, 0xF, 0xF, false));
}
// lane0 keeps old value (don't-care for index path)
__device__ __forceinline__ int dpp_shr1_i(int x) {
    return __builtin_amdgcn_update_dpp(x, x, 0x138, 0xF, 0xF, false);
}

// ---------------------------------------------------------------------------
// Kernel 0 (fused prep): blocks 0..127 pack xyz+|p|^2 into float4;
// block 128 folds BN params and collapses pf1+pf2 into a 3->64 affine.
// ---------------------------------------------------------------------------
__global__ __launch_bounds__(256) void prep_kernel(
    const float* __restrict__ inp, float4* __restrict__ pts,
    const float* __restrict__ bn_pf1, const float* __restrict__ bn_pf2,
    const float* __restrict__ bn_c1,  const float* __restrict__ bn_c2,
    const float* __restrict__ bn_c3,  const float* __restrict__ bn_f,
    const float* __restrict__ Wpf1,   const float* __restrict__ bpf1,
    const float* __restrict__ Wpf2,   const float* __restrict__ bpf2,
    float* __restrict__ wsf) {
    const int tid = threadIdx.x;
    if (blockIdx.x < 128) {
        int i = blockIdx.x * 256 + tid;
        const float* r = inp + (size_t)i * CH_;
        float x = r[0], y = r[1], z = r[2];
        float pp = __fadd_rn(__fadd_rn(__fmul_rn(x, x), __fmul_rn(y, y)),
                             __fmul_rn(z, z));
        pts[i] = make_float4(x, y, z, pp);
        return;
    }
#pragma unroll
    for (int it = 0; it < 4; ++it) {
        int t = it * 256 + tid;
        const float* src; int nch, c, so, sho;
        if (t < 64)       { src = bn_pf1; nch = 64;  c = t;        so = S_PF1; sho = SH_PF1; }
        else if (t < 128) { src = bn_pf2; nch = 64;  c = t - 64;   so = S_PF2; sho = SH_PF2; }
        else if (t < 384) { src = bn_c1;  nch = 256; c = t - 128;  so = S_C1;  sho = SH_C1; }
        else if (t < 640) { src = bn_c2;  nch = 256; c = t - 384;  so = S_C2;  sho = SH_C2; }
        else if (t < 896) { src = bn_c3;  nch = 256; c = t - 640;  so = S_C3;  sho = SH_C3; }
        else              { src = bn_f;   nch = 128; c = t - 896;  so = S_F;   sho = SH_F;  }
        float g = src[c], b = src[nch + c], m = src[2 * nch + c], v = src[3 * nch + c];
        float s = g * rsqrtf(v + 1e-3f);
        wsf[so + c]  = s;
        wsf[sho + c] = b - m * s;
    }
    __syncthreads();
    if (tid < 64) {
        int o = tid;
        float s2 = wsf[S_PF2 + o], t2 = wsf[SH_PF2 + o];
        float m0 = 0.f, m1 = 0.f, m2 = 0.f, cc = 0.f;
        for (int c = 0; c < 64; ++c) {
            float s1 = wsf[S_PF1 + c], t1 = wsf[SH_PF1 + c];
            float d1 = s1 * bpf1[c] + t1;
            float w2 = Wpf2[c * 64 + o];
            m0 += Wpf1[0 * 64 + c] * s1 * w2;
            m1 += Wpf1[1 * 64 + c] * s1 * w2;
            m2 += Wpf1[2 * 64 + c] * s1 * w2;
            cc += d1 * w2;
        }
        wsf[M_OFF + 0 * 64 + o] = m0 * s2;
        wsf[M_OFF + 1 * 64 + o] = m1 * s2;
        wsf[M_OFF + 2 * 64 + o] = m2 * s2;
        wsf[C0_OFF + o]         = cc * s2 + bpf2[o] * s2 + t2;
    }
}

// ---------------------------------------------------------------------------
// Kernel 1 (FUSED knn + pipeline): one wave = one query = one point.
// Phase 1: exact KNN, sorted top-32 across lanes 0..31 in registers
//   (bitwise-identical numerics: d2 = (qq+pp) - 2e, no FMA; strict-shift
//   stable insertion via DPP wave_shr1). No idx round-trip: neighbor k is
//   readlane(bi, 2k).
// Phase 2: stages A..H of the per-point pipeline (R5-verified arithmetic),
//   writing the dw row for the final GEMM.
// VALU-heavy phase-1 waves co-schedule with latency-bound phase-2 waves.
// ---------------------------------------------------------------------------
__global__ __launch_bounds__(256) void fused_kernel(
    const float4* __restrict__ pts, const float* __restrict__ inp,
    const float* __restrict__ Wc1,  const float* __restrict__ bc1,
    const float* __restrict__ Wc2,  const float* __restrict__ bc2,
    const float* __restrict__ Wc3,  const float* __restrict__ bc3,
    const float* __restrict__ Wdf,  const float* __restrict__ wsf,
    float* __restrict__ dwl, float* __restrict__ out) {

    __shared__ float xA[4][256];
    __shared__ float xB[4][256];

    const int w   = threadIdx.x >> 6;
    const int l   = threadIdx.x & 63;
    const int wid = (blockIdx.x << 2) | w;    // query/point id 0..8191
    const int b   = wid >> 10;
    const int qi  = wid & 1023;
    const float4* bp = pts + ((size_t)b << 12);

    const float4 q = bp[qi];
    const float qq = q.w;

#define DIST2(P) __fsub_rn(__fadd_rn(qq, (P).w), __fmul_rn(2.0f, \
    __fadd_rn(__fadd_rn(__fmul_rn(q.x, (P).x), __fmul_rn(q.y, (P).y)), \
              __fmul_rn(q.z, (P).z))))

    // issue upcoming candidate loads early so they overlap the bootstrap sort
    float4 p  = bp[l];
    float4 g1 = bp[64 + l];
    float4 g2 = bp[128 + l];
    float4 g3 = bp[192 + l];

    // ---- bootstrap: bitonic sort first 64 by (d2, idx) ascending
    float d = DIST2(p);
    int ii = l;
#pragma unroll
    for (int k = 2; k <= 64; k <<= 1) {
#pragma unroll
        for (int j = k >> 1; j > 0; j >>= 1) {
            float od = __shfl_xor(d, j);
            int   oi = __shfl_xor(ii, j);
            bool keepmin = (((l & k) == 0) == ((l & j) == 0));
            bool ol = (od < d) || (od == d && oi < ii);
            bool take = keepmin ? ol : !ol;
            if (take) { d = od; ii = oi; }
        }
    }
    float bd = d;      // lane s (<32): s-th smallest
    int   bi = ii;
    float kth = rlf(bd, 31);

#define INS_LOOP(MV, D2V, BASE)                                        \
    if (MV) {                                                          \
        do {                                                           \
            int c = (int)__builtin_ctzll(MV); MV &= MV - 1;            \
            float dc = rlf(D2V, c);                                    \
            int   ic = (BASE) + c;                                     \
            float prev  = dpp_shr1_ninf(bd);                           \
            int   previ = dpp_shr1_i(bi);                              \
            bool c1 = (bd > dc);                                       \
            bool c2 = (prev > dc);                                     \
            bd = fminf(bd, fmaxf(prev, dc));                           \
            bi = c1 ? (c2 ? previ : ic) : bi;                          \
        } while (MV);                                                  \
        kth = rlf(bd, 31);                                             \
    }

    {
        float d2 = DIST2(g1);
        unsigned long long m = __ballot(d2 < kth);
        INS_LOOP(m, d2, 64);
    }
    for (int j0 = 128; j0 < NIN_; j0 += 128) {
        float4 pa = g2, pb = g3;
        int jn = j0 + 128;
        if (jn < NIN_) { g2 = bp[jn + l]; g3 = bp[jn + 64 + l]; }
        float d2a = DIST2(pa);
        unsigned long long ma = __ballot(d2a < kth);
        INS_LOOP(ma, d2a, j0);
        float d2b = DIST2(pb);
        unsigned long long mb = __ballot(d2b < kth);
        INS_LOOP(mb, d2b, j0 + 64);
    }
#undef INS_LOOP
#undef DIST2

    // ======== Phase 2: per-point pipeline (R5-verified arithmetic) ========
    const float* brow = inp + (size_t)b * NIN_ * CH_;
    const float q0 = q.x, q1 = q.y, q2 = q.z;

    // ---- xyz gather: ONE load instr. lanes 0..47: k = l/3, d = l%3.
    float pd;
    {
        int k3 = (l * 21846) >> 16;          // l/3 for l < 48
        k3 = (k3 > 15) ? 15 : k3;
        int d3 = l - ((k3 << 1) + k3);
        d3 = (d3 > 2) ? 2 : d3;
        int nbl = __shfl(bi, k3 << 1);       // neighbor index at rank 2*k3
        float v = 0.f;
        if (l < 48) v = brow[(size_t)nbl * CH_ + d3];
        float qv = (d3 == 0) ? q0 : ((d3 == 1) ? q1 : q2);
        pd = v - qv;
    }

    // ---- Stage D: x1[o] = BN(elu(pnb48 . Wc1 + bc1)),  o = 4l+r
    {
        float4 acc = *reinterpret_cast<const float4*>(bc1 + 4 * l);
#pragma unroll 4
        for (int t4 = 0; t4 < 12; ++t4) {
            const float* wb = Wc1 + (size_t)(t4 * 4) * 256 + 4 * l;
            float4 w0 = *reinterpret_cast<const float4*>(wb);
            float4 w1 = *reinterpret_cast<const float4*>(wb + 256);
            float4 w2 = *reinterpret_cast<const float4*>(wb + 512);
            float4 w3 = *reinterpret_cast<const float4*>(wb + 768);
            float p0 = rlf(pd, 4 * t4 + 0);
            float p1 = rlf(pd, 4 * t4 + 1);
            float p2 = rlf(pd, 4 * t4 + 2);
            float p3 = rlf(pd, 4 * t4 + 3);
            acc.x += p0 * w0.x + p1 * w1.x + p2 * w2.x + p3 * w3.x;
            acc.y += p0 * w0.y + p1 * w1.y + p2 * w2.y + p3 * w3.y;
            acc.z += p0 * w0.z + p1 * w1.z + p2 * w2.z + p3 * w3.z;
            acc.w += p0 * w0.w + p1 * w1.w + p2 * w2.w + p3 * w3.w;
        }
        float4 sc = *reinterpret_cast<const float4*>(wsf + S_C1 + 4 * l);
        float4 sh = *reinterpret_cast<const float4*>(wsf + SH_C1 + 4 * l);
        float4 r;
        r.x = sc.x * eluf(acc.x) + sh.x;
        r.y = sc.y * eluf(acc.y) + sh.y;
        r.z = sc.z * eluf(acc.z) + sh.z;
        r.w = sc.w * eluf(acc.w) + sh.w;
        *reinterpret_cast<float4*>(&xA[w][4 * l]) = r;
    }

    // ---- Stage E: x2[o] = BN(elu(sum_w x1[w][c]*Wc2[w][o])),  c = l>>2
    {
        float4 acc = *reinterpret_cast<const float4*>(bc2 + 4 * l);
        const int csel = l >> 2;
#pragma unroll 8
        for (int w16 = 0; w16 < 16; ++w16) {
            float xs = xA[w][w16 * 16 + csel];
            float4 w4 = *reinterpret_cast<const float4*>(Wc2 + (size_t)w16 * 256 + 4 * l);
            acc.x += xs * w4.x; acc.y += xs * w4.y;
            acc.z += xs * w4.z; acc.w += xs * w4.w;
        }
        float4 sc = *reinterpret_cast<const float4*>(wsf + S_C2 + 4 * l);
        float4 sh = *reinterpret_cast<const float4*>(wsf + SH_C2 + 4 * l);
        float4 r;
        r.x = sc.x * eluf(acc.x) + sh.x;
        r.y = sc.y * eluf(acc.y) + sh.y;
        r.z = sc.z * eluf(acc.z) + sh.z;
        r.w = sc.w * eluf(acc.w) + sh.w;
        *reinterpret_cast<float4*>(&xB[w][4 * l]) = r;
    }

    // ---- Stage F: x3 (kept in registers, o = 4l..4l+3)
    float x3r[4];
    {
        float4 acc = *reinterpret_cast<const float4*>(bc3 + 4 * l);
        const int csel = l >> 2;
#pragma unroll 8
        for (int w16 = 0; w16 < 16; ++w16) {
            float xs = xB[w][w16 * 16 + csel];
            float4 w4 = *reinterpret_cast<const float4*>(Wc3 + (size_t)w16 * 256 + 4 * l);
            acc.x += xs * w4.x; acc.y += xs * w4.y;
            acc.z += xs * w4.z; acc.w += xs * w4.w;
        }
        float4 sc = *reinterpret_cast<const float4*>(wsf + S_C3 + 4 * l);
        float4 sh = *reinterpret_cast<const float4*>(wsf + SH_C3 + 4 * l);
        x3r[0] = sc.x * eluf(acc.x) + sh.x;
        x3r[1] = sc.y * eluf(acc.y) + sh.y;
        x3r[2] = sc.z * eluf(acc.z) + sh.z;
        x3r[3] = sc.w * eluf(acc.w) + sh.w;
    }

    // ---- h2 (fused pf) from readlanes of pd (short liveness)
    float h2[16];
    {
        const float Mw0 = wsf[M_OFF + l];
        const float Mw1 = wsf[M_OFF + 64 + l];
        const float Mw2 = wsf[M_OFF + 128 + l];
        const float cc0 = wsf[C0_OFF + l];
#pragma unroll
        for (int k = 0; k < 16; ++k) {
            float s0 = rlf(pd, 3 * k), s1 = rlf(pd, 3 * k + 1), s2 = rlf(pd, 3 * k + 2);
            h2[k] = fmaf(s0, Mw0, fmaf(s1, Mw1, fmaf(s2, Mw2, cc0)));
        }
    }

    // ---- fnb loaded from global (uniform row bases via readlane of bi)
    float fnb[16];
#pragma unroll
    for (int k = 0; k < 16; ++k) {
        int nbs = rli(bi, 2 * k);
        fnb[k] = brow[(size_t)nbs * CH_ + 3 + l];
    }

    // ---- Stage G+H fused: feat2 row i folded straight into dw
    float d00 = 0.f, d01 = 0.f, d10 = 0.f, d11 = 0.f;
#pragma unroll 4
    for (int i = 0; i < 16; ++i) {
        float fa = 0.f, fb = 0.f;
#pragma unroll
        for (int j = 0; j < 16; ++j) {
            float xv = rlf(x3r[j & 3], i * 4 + (j >> 2));
            fa += xv * h2[j];
            fb += xv * fnb[j];
        }
        const float* wr = Wdf + (size_t)i * 256;
        float2 wlo = *reinterpret_cast<const float2*>(wr + 2 * l);
        float2 whi = *reinterpret_cast<const float2*>(wr + 128 + 2 * l);
        d00 += fa * wlo.x; d01 += fa * wlo.y;
        d10 += fb * whi.x; d11 += fb * whi.y;
    }
    float* drow = dwl + (size_t)wid * 256;
    *reinterpret_cast<float2*>(drow + 2 * l)       = make_float2(d00, d01);
    *reinterpret_cast<float2*>(drow + 128 + 2 * l) = make_float2(d10, d11);

    if (l < 3) out[(size_t)wid * 131 + l] = (l == 0) ? q0 : ((l == 1) ? q1 : q2);
}

// ---------------------------------------------------------------------------
// Kernel 2: final pointwise layer as tiled f32 GEMM: M=8192 K=256 N=128.
// ---------------------------------------------------------------------------
__global__ __launch_bounds__(256) void pw_kernel(const float* __restrict__ dwl,
                                                 const float* __restrict__ Wpw,
                                                 const float* __restrict__ bf,
                                                 const float* __restrict__ wsf,
                                                 float* __restrict__ out) {
    __shared__ float As[32][256];
    const int tid = threadIdx.x;
    const int m0  = blockIdx.x * 32;

#pragma unroll
    for (int i = 0; i < 8; ++i) {
        int fi  = i * 1024 + tid * 4;
        int row = fi >> 8, col = fi & 255;
        *reinterpret_cast<float4*>(&As[row][col]) =
            *reinterpret_cast<const float4*>(dwl + (size_t)(m0 + row) * 256 + col);
    }
    __syncthreads();

    const int mq = tid >> 5;          // 8 m-quads
    const int nq = tid & 31;          // 32 n-quads
    float acc[4][4];
#pragma unroll
    for (int mi = 0; mi < 4; ++mi)
#pragma unroll
        for (int ni = 0; ni < 4; ++ni) acc[mi][ni] = 0.f;

#pragma unroll 4
    for (int k4 = 0; k4 < 64; ++k4) {
        float4 a[4], bw[4];
#pragma unroll
        for (int mi = 0; mi < 4; ++mi)
            a[mi] = *reinterpret_cast<const float4*>(&As[mq * 4 + mi][k4 * 4]);
#pragma unroll
        for (int ki = 0; ki < 4; ++ki)
            bw[ki] = *reinterpret_cast<const float4*>(Wpw + (size_t)(k4 * 4 + ki) * 128 + nq * 4);
#pragma unroll
        for (int mi = 0; mi < 4; ++mi) {
            const float4 am = a[mi];
            acc[mi][0] += am.x * bw[0].x + am.y * bw[1].x + am.z * bw[2].x + am.w * bw[3].x;
            acc[mi][1] += am.x * bw[0].y + am.y * bw[1].y + am.z * bw[2].y + am.w * bw[3].y;
            acc[mi][2] += am.x * bw[0].z + am.y * bw[1].z + am.z * bw[2].z + am.w * bw[3].z;
            acc[mi][3] += am.x * bw[0].w + am.y * bw[1].w + am.z * bw[2].w + am.w * bw[3].w;
        }
    }

    float4 b4  = *reinterpret_cast<const float4*>(bf + nq * 4);
    float4 sc4 = *reinterpret_cast<const float4*>(wsf + S_F + nq * 4);
    float4 sh4 = *reinterpret_cast<const float4*>(wsf + SH_F + nq * 4);
#pragma unroll
    for (int mi = 0; mi < 4; ++mi) {
        const int m = m0 + mq * 4 + mi;
        float* orow = out + (size_t)m * 131 + 3 + nq * 4;
        orow[0] = sc4.x * eluf(acc[mi][0] + b4.x) + sh4.x;
        orow[1] = sc4.y * eluf(acc[mi][1] + b4.y) + sh4.y;
        orow[2] = sc4.z * eluf(acc[mi][2] + b4.z) + sh4.z;
        orow[3] = sc4.w * eluf(acc[mi][3] + b4.w) + sh4.w;
    }
}

// ---------------------------------------------------------------------------
extern "C" void kernel_launch(void* const* d_in, const int* in_sizes, int n_in,
                              void* d_out, int out_size, void* d_ws, size_t ws_size,
                              hipStream_t stream) {
    const float* inp   = (const float*)d_in[0];
    const float* Wpf1  = (const float*)d_in[1];
    const float* bpf1  = (const float*)d_in[2];
    const float* bnpf1 = (const float*)d_in[3];
    const float* Wpf2  = (const float*)d_in[4];
    const float* bpf2  = (const float*)d_in[5];
    const float* bnpf2 = (const float*)d_in[6];
    const float* Wc1   = (const float*)d_in[7];
    const float* bc1   = (const float*)d_in[8];
    const float* bnc1  = (const float*)d_in[9];
    const float* Wc2   = (const float*)d_in[10];
    const float* bc2   = (const float*)d_in[11];
    const float* bnc2  = (const float*)d_in[12];
    const float* Wc3   = (const float*)d_in[13];
    const float* bc3   = (const float*)d_in[14];
    const float* bnc3  = (const float*)d_in[15];
    const float* Wdf   = (const float*)d_in[16];
    const float* Wpw   = (const float*)d_in[17];
    const float* bf    = (const float*)d_in[18];
    const float* bnf   = (const float*)d_in[19];

    float*  wsf  = (float*)d_ws;
    float4* pts  = (float4*)((char*)d_ws + WS_PTS_OFF);
    float*  dwl  = (float*)((char*)d_ws + WS_DWL_OFF);
    float*  outp = (float*)d_out;

    hipLaunchKernelGGL(prep_kernel, dim3(129), dim3(256), 0, stream,
                       inp, pts, bnpf1, bnpf2, bnc1, bnc2, bnc3, bnf,
                       Wpf1, bpf1, Wpf2, bpf2, wsf);
    hipLaunchKernelGGL(fused_kernel, dim3((B_ * P_) / 4), dim3(256), 0, stream,
                       pts, inp, Wc1, bc1, Wc2, bc2, Wc3, bc3, Wdf, wsf,
                       dwl, outp);
    hipLaunchKernelGGL(pw_kernel, dim3((B_ * P_) / 32), dim3(256), 0, stream,
                       dwl, Wpw, bf, wsf, outp);
}

// Round 9
// 105.780 us; speedup vs baseline: 3.4986x; 1.1484x over previous
//
#include <hip/hip_runtime.h>
#include <math.h>

#define B_    8
#define NIN_  4096
#define P_    1024
#define K_    16
#define F_    64
#define CH_   67      // 3 + F
#define CPF_  64
#define CIN_  128
#define C_    128

// ---- ws float-offset layout ----
#define S_PF1  0
#define SH_PF1 64
#define S_PF2  128
#define SH_PF2 192
#define S_C1   256
#define SH_C1  512
#define S_C2   768
#define SH_C2  1024
#define S_C3   1280
#define SH_C3  1536
#define S_F    1792
#define SH_F   1920
#define M_OFF  2048     // fused pf matrix 3x64
#define C0_OFF 2240     // fused pf bias 64

// byte offsets in ws
#define WS_PTS_OFF  16384
#define WS_DWL_OFF  (WS_PTS_OFF + B_ * NIN_ * 16)          // 540672

typedef float f2 __attribute__((ext_vector_type(2)));
typedef float f4 __attribute__((ext_vector_type(4)));

__device__ __forceinline__ float rlf(float x, int l) {
    return __int_as_float(__builtin_amdgcn_readlane(__float_as_int(x), l));
}
__device__ __forceinline__ int rli(int x, int l) {
    return __builtin_amdgcn_readlane(x, l);
}
__device__ __forceinline__ float eluf(float z) {
    return z > 0.f ? z : (__expf(z) - 1.0f);
}
// whole-wave shift-right-by-1 via DPP (VALU). lane0 receives -inf.
__device__ __forceinline__ float dpp_shr1_ninf(float x) {
    return __int_as_float(__builtin_amdgcn_update_dpp(
        (int)0xFF800000, __float_as_int(x), 0x138, 0xF, 0xF, false));
}
// lane0 keeps old value (don't-care for index path)
__device__ __forceinline__ int dpp_shr1_i(int x) {
    return __builtin_amdgcn_update_dpp(x, x, 0x138, 0xF, 0xF, false);
}

// ---------------------------------------------------------------------------
// Kernel 0 (fused prep): blocks 0..127 pack xyz+|p|^2 into float4;
// block 128 folds BN params and collapses pf1+pf2 into a 3->64 affine.
// ---------------------------------------------------------------------------
__global__ __launch_bounds__(256) void prep_kernel(
    const float* __restrict__ inp, float4* __restrict__ pts,
    const float* __restrict__ bn_pf1, const float* __restrict__ bn_pf2,
    const float* __restrict__ bn_c1,  const float* __restrict__ bn_c2,
    const float* __restrict__ bn_c3,  const float* __restrict__ bn_f,
    const float* __restrict__ Wpf1,   const float* __restrict__ bpf1,
    const float* __restrict__ Wpf2,   const float* __restrict__ bpf2,
    float* __restrict__ wsf) {
    const int tid = threadIdx.x;
    if (blockIdx.x < 128) {
        int i = blockIdx.x * 256 + tid;
        const float* r = inp + (size_t)i * CH_;
        float x = r[0], y = r[1], z = r[2];
        float pp = __fadd_rn(__fadd_rn(__fmul_rn(x, x), __fmul_rn(y, y)),
                             __fmul_rn(z, z));
        pts[i] = make_float4(x, y, z, pp);
        return;
    }
#pragma unroll
    for (int it = 0; it < 4; ++it) {
        int t = it * 256 + tid;
        const float* src; int nch, c, so, sho;
        if (t < 64)       { src = bn_pf1; nch = 64;  c = t;        so = S_PF1; sho = SH_PF1; }
        else if (t < 128) { src = bn_pf2; nch = 64;  c = t - 64;   so = S_PF2; sho = SH_PF2; }
        else if (t < 384) { src = bn_c1;  nch = 256; c = t - 128;  so = S_C1;  sho = SH_C1; }
        else if (t < 640) { src = bn_c2;  nch = 256; c = t - 384;  so = S_C2;  sho = SH_C2; }
        else if (t < 896) { src = bn_c3;  nch = 256; c = t - 640;  so = S_C3;  sho = SH_C3; }
        else              { src = bn_f;   nch = 128; c = t - 896;  so = S_F;   sho = SH_F;  }
        float g = src[c], b = src[nch + c], m = src[2 * nch + c], v = src[3 * nch + c];
        float s = g * rsqrtf(v + 1e-3f);
        wsf[so + c]  = s;
        wsf[sho + c] = b - m * s;
    }
    __syncthreads();
    if (tid < 64) {
        int o = tid;
        float s2 = wsf[S_PF2 + o], t2 = wsf[SH_PF2 + o];
        float m0 = 0.f, m1 = 0.f, m2 = 0.f, cc = 0.f;
        for (int c = 0; c < 64; ++c) {
            float s1 = wsf[S_PF1 + c], t1 = wsf[SH_PF1 + c];
            float d1 = s1 * bpf1[c] + t1;
            float w2 = Wpf2[c * 64 + o];
            m0 += Wpf1[0 * 64 + c] * s1 * w2;
            m1 += Wpf1[1 * 64 + c] * s1 * w2;
            m2 += Wpf1[2 * 64 + c] * s1 * w2;
            cc += d1 * w2;
        }
        wsf[M_OFF + 0 * 64 + o] = m0 * s2;
        wsf[M_OFF + 1 * 64 + o] = m1 * s2;
        wsf[M_OFF + 2 * 64 + o] = m2 * s2;
        wsf[C0_OFF + o]         = cc * s2 + bpf2[o] * s2 + t2;
    }
}

// ---------------------------------------------------------------------------
// Kernel 1 (FUSED knn + pipeline): one wave = one query = one point.
// Phase 1: exact KNN (byte-identical to R8): sorted top-32 across lanes 0..31,
//   d2 = (qq+pp) - 2e with no FMA; strict-shift stable insertion via DPP.
// Phase 2: pipeline with packed-f32 math (v_pk_fma) and LDS-broadcast X3.
// ---------------------------------------------------------------------------
__global__ __launch_bounds__(256) void fused_kernel(
    const float4* __restrict__ pts, const float* __restrict__ inp,
    const float* __restrict__ Wc1,  const float* __restrict__ bc1,
    const float* __restrict__ Wc2,  const float* __restrict__ bc2,
    const float* __restrict__ Wc3,  const float* __restrict__ bc3,
    const float* __restrict__ Wdf,  const float* __restrict__ wsf,
    float* __restrict__ dwl, float* __restrict__ out) {

    __shared__ float xA[4][256];
    __shared__ float xB[4][256];

    const int w   = threadIdx.x >> 6;
    const int l   = threadIdx.x & 63;
    const int wid = (blockIdx.x << 2) | w;    // query/point id 0..8191
    const int b   = wid >> 10;
    const int qi  = wid & 1023;
    const float4* bp = pts + ((size_t)b << 12);

    const float4 q = bp[qi];
    const float qq = q.w;

#define DIST2(P) __fsub_rn(__fadd_rn(qq, (P).w), __fmul_rn(2.0f, \
    __fadd_rn(__fadd_rn(__fmul_rn(q.x, (P).x), __fmul_rn(q.y, (P).y)), \
              __fmul_rn(q.z, (P).z))))

    // issue upcoming candidate loads early so they overlap the bootstrap sort
    float4 p  = bp[l];
    float4 g1 = bp[64 + l];
    float4 g2 = bp[128 + l];
    float4 g3 = bp[192 + l];

    // ---- bootstrap: bitonic sort first 64 by (d2, idx) ascending
    float d = DIST2(p);
    int ii = l;
#pragma unroll
    for (int k = 2; k <= 64; k <<= 1) {
#pragma unroll
        for (int j = k >> 1; j > 0; j >>= 1) {
            float od = __shfl_xor(d, j);
            int   oi = __shfl_xor(ii, j);
            bool keepmin = (((l & k) == 0) == ((l & j) == 0));
            bool ol = (od < d) || (od == d && oi < ii);
            bool take = keepmin ? ol : !ol;
            if (take) { d = od; ii = oi; }
        }
    }
    float bd = d;      // lane s (<32): s-th smallest
    int   bi = ii;
    float kth = rlf(bd, 31);

#define INS_LOOP(MV, D2V, BASE)                                        \
    if (MV) {                                                          \
        do {                                                           \
            int c = (int)__builtin_ctzll(MV); MV &= MV - 1;            \
            float dc = rlf(D2V, c);                                    \
            int   ic = (BASE) + c;                                     \
            float prev  = dpp_shr1_ninf(bd);                           \
            int   previ = dpp_shr1_i(bi);                              \
            bool c1 = (bd > dc);                                       \
            bool c2 = (prev > dc);                                     \
            bd = fminf(bd, fmaxf(prev, dc));                           \
            bi = c1 ? (c2 ? previ : ic) : bi;                          \
        } while (MV);                                                  \
        kth = rlf(bd, 31);                                             \
    }

    {
        float d2 = DIST2(g1);
        unsigned long long m = __ballot(d2 < kth);
        INS_LOOP(m, d2, 64);
    }
    for (int j0 = 128; j0 < NIN_; j0 += 128) {
        float4 pa = g2, pb = g3;
        int jn = j0 + 128;
        if (jn < NIN_) { g2 = bp[jn + l]; g3 = bp[jn + 64 + l]; }
        float d2a = DIST2(pa);
        unsigned long long ma = __ballot(d2a < kth);
        INS_LOOP(ma, d2a, j0);
        float d2b = DIST2(pb);
        unsigned long long mb = __ballot(d2b < kth);
        INS_LOOP(mb, d2b, j0 + 64);
    }
#undef INS_LOOP
#undef DIST2

    // ======== Phase 2: per-point pipeline (packed f32 math) ========
    const float* brow = inp + (size_t)b * NIN_ * CH_;
    const float q0 = q.x, q1 = q.y, q2 = q.z;

    // ---- xyz gather: ONE load instr. lanes 0..47: k = l/3, d = l%3.
    float pd;
    {
        int k3 = (l * 21846) >> 16;          // l/3 for l < 48
        k3 = (k3 > 15) ? 15 : k3;
        int d3 = l - ((k3 << 1) + k3);
        d3 = (d3 > 2) ? 2 : d3;
        int nbl = __shfl(bi, k3 << 1);       // neighbor index at rank 2*k3
        float v = 0.f;
        if (l < 48) v = brow[(size_t)nbl * CH_ + d3];
        float qv = (d3 == 0) ? q0 : ((d3 == 1) ? q1 : q2);
        pd = v - qv;
    }

    // ---- Stage D: x1[o] = BN(elu(pnb48 . Wc1 + bc1)),  o = 4l+r
    {
        f4 acc = *reinterpret_cast<const f4*>(bc1 + 4 * l);
#pragma unroll 4
        for (int t4 = 0; t4 < 12; ++t4) {
            const float* wb = Wc1 + (size_t)(t4 * 4) * 256 + 4 * l;
            f4 w0 = *reinterpret_cast<const f4*>(wb);
            f4 w1 = *reinterpret_cast<const f4*>(wb + 256);
            f4 w2 = *reinterpret_cast<const f4*>(wb + 512);
            f4 w3 = *reinterpret_cast<const f4*>(wb + 768);
            float p0 = rlf(pd, 4 * t4 + 0);
            float p1 = rlf(pd, 4 * t4 + 1);
            float p2 = rlf(pd, 4 * t4 + 2);
            float p3 = rlf(pd, 4 * t4 + 3);
            acc += p0 * w0 + p1 * w1 + p2 * w2 + p3 * w3;
        }
        f4 sc = *reinterpret_cast<const f4*>(wsf + S_C1 + 4 * l);
        f4 sh = *reinterpret_cast<const f4*>(wsf + SH_C1 + 4 * l);
        f4 r;
        r.x = sc.x * eluf(acc.x) + sh.x;
        r.y = sc.y * eluf(acc.y) + sh.y;
        r.z = sc.z * eluf(acc.z) + sh.z;
        r.w = sc.w * eluf(acc.w) + sh.w;
        *reinterpret_cast<f4*>(&xA[w][4 * l]) = r;
    }

    // ---- Stage E: x2[o] = BN(elu(sum_w x1[w][c]*Wc2[w][o])),  c = l>>2
    {
        f4 acc = *reinterpret_cast<const f4*>(bc2 + 4 * l);
        const int csel = l >> 2;
#pragma unroll 8
        for (int w16 = 0; w16 < 16; ++w16) {
            float xs = xA[w][w16 * 16 + csel];
            f4 w4 = *reinterpret_cast<const f4*>(Wc2 + (size_t)w16 * 256 + 4 * l);
            acc += xs * w4;
        }
        f4 sc = *reinterpret_cast<const f4*>(wsf + S_C2 + 4 * l);
        f4 sh = *reinterpret_cast<const f4*>(wsf + SH_C2 + 4 * l);
        f4 r;
        r.x = sc.x * eluf(acc.x) + sh.x;
        r.y = sc.y * eluf(acc.y) + sh.y;
        r.z = sc.z * eluf(acc.z) + sh.z;
        r.w = sc.w * eluf(acc.w) + sh.w;
        *reinterpret_cast<f4*>(&xB[w][4 * l]) = r;
    }

    // ---- Stage F: x3 -> straight into LDS (xA reused) for broadcast reads
    {
        f4 acc = *reinterpret_cast<const f4*>(bc3 + 4 * l);
        const int csel = l >> 2;
#pragma unroll 8
        for (int w16 = 0; w16 < 16; ++w16) {
            float xs = xB[w][w16 * 16 + csel];
            f4 w4 = *reinterpret_cast<const f4*>(Wc3 + (size_t)w16 * 256 + 4 * l);
            acc += xs * w4;
        }
        f4 sc = *reinterpret_cast<const f4*>(wsf + S_C3 + 4 * l);
        f4 sh = *reinterpret_cast<const f4*>(wsf + SH_C3 + 4 * l);
        f4 r;
        r.x = sc.x * eluf(acc.x) + sh.x;
        r.y = sc.y * eluf(acc.y) + sh.y;
        r.z = sc.z * eluf(acc.z) + sh.z;
        r.w = sc.w * eluf(acc.w) + sh.w;
        *reinterpret_cast<f4*>(&xA[w][4 * l]) = r;   // X3 element o = 4l+r
    }

    // ---- hf[k] = (h2[k], fnb[k]) pairs for packed G+H
    f2 hf[16];
    {
        const float Mw0 = wsf[M_OFF + l];
        const float Mw1 = wsf[M_OFF + 64 + l];
        const float Mw2 = wsf[M_OFF + 128 + l];
        const float cc0 = wsf[C0_OFF + l];
#pragma unroll
        for (int k = 0; k < 16; ++k) {
            int nbs = rli(bi, 2 * k);
            float fv = brow[(size_t)nbs * CH_ + 3 + l];
            float s0 = rlf(pd, 3 * k), s1 = rlf(pd, 3 * k + 1), s2 = rlf(pd, 3 * k + 2);
            float hv = fmaf(s0, Mw0, fmaf(s1, Mw1, fmaf(s2, Mw2, cc0)));
            f2 t; t.x = hv; t.y = fv;
            hf[k] = t;
        }
    }

    // ---- Stage G+H fused (packed): X3 rows via LDS broadcast b128 reads
    f2 dlo; dlo.x = 0.f; dlo.y = 0.f;
    f2 dhi = dlo;
#pragma unroll 4
    for (int i = 0; i < 16; ++i) {
        const f4* xr = reinterpret_cast<const f4*>(&xA[w][i * 16]);
        f4 x0 = xr[0], x1 = xr[1], x2 = xr[2], x3v = xr[3];
        f2 fab = x0.x * hf[0]  + x0.y * hf[1]  + x0.z * hf[2]  + x0.w * hf[3]
               + x1.x * hf[4]  + x1.y * hf[5]  + x1.z * hf[6]  + x1.w * hf[7]
               + x2.x * hf[8]  + x2.y * hf[9]  + x2.z * hf[10] + x2.w * hf[11]
               + x3v.x * hf[12]+ x3v.y * hf[13]+ x3v.z * hf[14]+ x3v.w * hf[15];
        const float* wr = Wdf + (size_t)i * 256;
        f2 wlo = *reinterpret_cast<const f2*>(wr + 2 * l);
        f2 whi = *reinterpret_cast<const f2*>(wr + 128 + 2 * l);
        dlo += fab.x * wlo;
        dhi += fab.y * whi;
    }
    float* drow = dwl + (size_t)wid * 256;
    *reinterpret_cast<f2*>(drow + 2 * l)       = dlo;
    *reinterpret_cast<f2*>(drow + 128 + 2 * l) = dhi;

    if (l < 3) out[(size_t)wid * 131 + l] = (l == 0) ? q0 : ((l == 1) ? q1 : q2);
}

// ---------------------------------------------------------------------------
// Kernel 2: final pointwise layer as tiled f32 GEMM: M=8192 K=256 N=128.
// Packed-f32 accumulators (v_pk_fma).
// ---------------------------------------------------------------------------
__global__ __launch_bounds__(256) void pw_kernel(const float* __restrict__ dwl,
                                                 const float* __restrict__ Wpw,
                                                 const float* __restrict__ bf,
                                                 const float* __restrict__ wsf,
                                                 float* __restrict__ out) {
    __shared__ float As[32][256];
    const int tid = threadIdx.x;
    const int m0  = blockIdx.x * 32;

#pragma unroll
    for (int i = 0; i < 8; ++i) {
        int fi  = i * 1024 + tid * 4;
        int row = fi >> 8, col = fi & 255;
        *reinterpret_cast<float4*>(&As[row][col]) =
            *reinterpret_cast<const float4*>(dwl + (size_t)(m0 + row) * 256 + col);
    }
    __syncthreads();

    const int mq = tid >> 5;          // 8 m-quads
    const int nq = tid & 31;          // 32 n-quads
    f4 acc[4];
#pragma unroll
    for (int mi = 0; mi < 4; ++mi) { acc[mi].x = 0.f; acc[mi].y = 0.f; acc[mi].z = 0.f; acc[mi].w = 0.f; }

#pragma unroll 4
    for (int k4 = 0; k4 < 64; ++k4) {
        f4 a[4], bw[4];
#pragma unroll
        for (int mi = 0; mi < 4; ++mi)
            a[mi] = *reinterpret_cast<const f4*>(&As[mq * 4 + mi][k4 * 4]);
#pragma unroll
        for (int ki = 0; ki < 4; ++ki)
            bw[ki] = *reinterpret_cast<const f4*>(Wpw + (size_t)(k4 * 4 + ki) * 128 + nq * 4);
#pragma unroll
        for (int mi = 0; mi < 4; ++mi) {
            acc[mi] += a[mi].x * bw[0] + a[mi].y * bw[1] + a[mi].z * bw[2] + a[mi].w * bw[3];
        }
    }

    f4 b4  = *reinterpret_cast<const f4*>(bf + nq * 4);
    f4 sc4 = *reinterpret_cast<const f4*>(wsf + S_F + nq * 4);
    f4 sh4 = *reinterpret_cast<const f4*>(wsf + SH_F + nq * 4);
#pragma unroll
    for (int mi = 0; mi < 4; ++mi) {
        const int m = m0 + mq * 4 + mi;
        float* orow = out + (size_t)m * 131 + 3 + nq * 4;
        orow[0] = sc4.x * eluf(acc[mi].x + b4.x) + sh4.x;
        orow[1] = sc4.y * eluf(acc[mi].y + b4.y) + sh4.y;
        orow[2] = sc4.z * eluf(acc[mi].z + b4.z) + sh4.z;
        orow[3] = sc4.w * eluf(acc[mi].w + b4.w) + sh4.w;
    }
}

// ---------------------------------------------------------------------------
extern "C" void kernel_launch(void* const* d_in, const int* in_sizes, int n_in,
                              void* d_out, int out_size, void* d_ws, size_t ws_size,
                              hipStream_t stream) {
    const float* inp   = (const float*)d_in[0];
    const float* Wpf1  = (const float*)d_in[1];
    const float* bpf1  = (const float*)d_in[2];
    const float* bnpf1 = (const float*)d_in[3];
    const float* Wpf2  = (const float*)d_in[4];
    const float* bpf2  = (const float*)d_in[5];
    const float* bnpf2 = (const float*)d_in[6];
    const float* Wc1   = (const float*)d_in[7];
    const float* bc1   = (const float*)d_in[8];
    const float* bnc1  = (const float*)d_in[9];
    const float* Wc2   = (const float*)d_in[10];
    const float* bc2   = (const float*)d_in[11];
    const float* bnc2  = (const float*)d_in[12];
    const float* Wc3   = (const float*)d_in[13];
    const float* bc3   = (const float*)d_in[14];
    const float* bnc3  = (const float*)d_in[15];
    const float* Wdf   = (const float*)d_in[16];
    const float* Wpw   = (const float*)d_in[17];
    const float* bf    = (const float*)d_in[18];
    const float* bnf   = (const float*)d_in[19];

    float*  wsf  = (float*)d_ws;
    float4* pts  = (float4*)((char*)d_ws + WS_PTS_OFF);
    float*  dwl  = (float*)((char*)d_ws + WS_DWL_OFF);
    float*  outp = (float*)d_out;

    hipLaunchKernelGGL(prep_kernel, dim3(129), dim3(256), 0, stream,
                       inp, pts, bnpf1, bnpf2, bnc1, bnc2, bnc3, bnf,
                       Wpf1, bpf1, Wpf2, bpf2, wsf);
    hipLaunchKernelGGL(fused_kernel, dim3((B_ * P_) / 4), dim3(256), 0, stream,
                       pts, inp, Wc1, bc1, Wc2, bc2, Wc3, bc3, Wdf, wsf,
                       dwl, outp);
    hipLaunchKernelGGL(pw_kernel, dim3((B_ * P_) / 32), dim3(256), 0, stream,
                       dwl, Wpw, bf, wsf, outp);
}